// Round 3
// baseline (985.371 us; speedup 1.0000x reference)
//
#include <hip/hip_runtime.h>

// Per-node MLP 16->256->128->6->128->256->1 (tanh...sigmoid) on
// edge_attr.reshape(500000,16). x / edge_index are dead inputs.
//
// f16 MFMA 16x16x32, feature-major activations. Weights pre-fragmented to
// A-operand layout in g_img; each block stages them to LDS once
// (global_load_lds w=16) and pushes 32 nodes/wave through all layers.
// R3: C->B shuffle transform fused into each layer's mi-loop so the full
// C-frag array and the full next-B array are never live together (R2 spilled
// ~1.9GB to scratch); occupancy pinned 2 waves/EU -> 256-VGPR budget.

#define N_NODES 500000

// ---- weight-image layout (bytes). All offsets 16B-aligned. ----
#define OFF_W1 0        // 16 blocks x 512B (L1: K=16 -> lanes 0..31 hold data)
#define OFF_W2 8192     // 64 blocks x 1KB  (L2: 256->128, mi*8+ki)
#define OFF_W3 73728    // 4  blocks x 1KB  (L3: 128->16(6 valid), ki)
#define OFF_W4 77824    // 8  blocks x 1KB  (L4: 6(pad32)->128, mi)
#define OFF_W5 86016    // 64 blocks x 1KB  (L5: 128->256, mi*4+ki)
#define OFF_WO 151552   // 256 f32 (output weights)
#define OFF_B1 152576   // 256 f32
#define OFF_B2 153600   // 128 f32
#define OFF_B3 154112   // 16  f32 (6 valid, rest 0)
#define OFF_B4 154176   // 128 f32
#define OFF_B5 154688   // 256 f32
#define IMG_BYTES 155712
// 16B chunks: 9732 = 19 rounds x 8 waves x 64 lanes + 4 tail chunks

typedef _Float16 half8  __attribute__((ext_vector_type(8)));
typedef __fp16   pk16x2 __attribute__((ext_vector_type(2)));
typedef float    f32x4  __attribute__((ext_vector_type(4)));

__device__ __align__(16) char g_img[IMG_BYTES];

union H8 { half8 h; int i[4]; };

static __device__ __forceinline__ unsigned pack_f16_rne(float a, float b) {
  _Float16 ha = (_Float16)a, hb = (_Float16)b;
  unsigned short ua = __builtin_bit_cast(unsigned short, ha);
  unsigned short ub = __builtin_bit_cast(unsigned short, hb);
  return (unsigned)ua | ((unsigned)ub << 16);
}

static __device__ __forceinline__ int pkrtz(float a, float b) {
  pk16x2 h = __builtin_amdgcn_cvt_pkrtz(a, b);
  return __builtin_bit_cast(int, h);
}

static __device__ __forceinline__ float tanh_f(float x) {
  float e = __builtin_amdgcn_exp2f(x * 2.8853900817779268f);
  float r = __builtin_amdgcn_rcpf(e + 1.0f);
  return __builtin_fmaf(-2.0f, r, 1.0f);
}

static __device__ __forceinline__ float sigmoid_f(float x) {
  float e = __builtin_amdgcn_exp2f(x * -1.4426950408889634f);
  return __builtin_amdgcn_rcpf(1.0f + e);
}

static __device__ __forceinline__ f32x4 MFMA(const H8& A, const int* b, f32x4 acc) {
  H8 B; B.i[0] = b[0]; B.i[1] = b[1]; B.i[2] = b[2]; B.i[3] = b[3];
  return __builtin_amdgcn_mfma_f32_16x16x32_f16(A.h, B.h, acc, 0, 0, 0);
}

// ---------------- prep: gather/transpose/convert weights into g_img ----------------
// A-fragment layout per 1KB block (mi,ki): lane L holds 16B = 8 f16 =
// W^T[16*mi + (L&15)][32*ki + 8*(L>>4) + 0..7]
__global__ void gnn_prep(const float* __restrict__ W1,  const float* __restrict__ b1,
                         const float* __restrict__ We1, const float* __restrict__ be1,
                         const float* __restrict__ We2, const float* __restrict__ be2,
                         const float* __restrict__ Wd1, const float* __restrict__ bd1,
                         const float* __restrict__ Wd2, const float* __restrict__ bd2,
                         const float* __restrict__ Wo)
{
  int t = blockIdx.x * 256 + threadIdx.x;
  int off = t * 4;
  if (off >= IMG_BYTES) return;
  unsigned val;
  if (off < OFF_W2) {                     // L1 (K=16): 512B half-blocks
    int rel = off;
    int mi = rel >> 9, li = (rel >> 4) & 31, j2 = (rel >> 2) & 3;
    int fout = mi * 16 + (li & 15);
    int k0 = (li >> 4) * 8 + j2 * 2;
    val = pack_f16_rne(W1[k0 * 256 + fout], W1[(k0 + 1) * 256 + fout]);
  } else if (off < OFF_W3) {              // L2: 256->128
    int rel = off - OFF_W2;
    int blk = rel >> 10, li = (rel >> 4) & 63, j2 = (rel >> 2) & 3;
    int mi = blk >> 3, ki = blk & 7;
    int fout = mi * 16 + (li & 15);
    int k0 = ki * 32 + (li >> 4) * 8 + j2 * 2;
    val = pack_f16_rne(We1[k0 * 128 + fout], We1[(k0 + 1) * 128 + fout]);
  } else if (off < OFF_W4) {              // L3: 128->6 (fout padded to 16)
    int rel = off - OFF_W3;
    int ki = rel >> 10, li = (rel >> 4) & 63, j2 = (rel >> 2) & 3;
    int fo = li & 15;
    int k0 = ki * 32 + (li >> 4) * 8 + j2 * 2;
    float a = (fo < 6) ? We2[k0 * 6 + fo] : 0.0f;
    float b = (fo < 6) ? We2[(k0 + 1) * 6 + fo] : 0.0f;
    val = pack_f16_rne(a, b);
  } else if (off < OFF_W5) {              // L4: 6->128 (K padded to 32)
    int rel = off - OFF_W4;
    int mi = rel >> 10, li = (rel >> 4) & 63, j2 = (rel >> 2) & 3;
    int fout = mi * 16 + (li & 15);
    int k0 = (li >> 4) * 8 + j2 * 2;
    float a = (k0 < 6)     ? Wd1[k0 * 128 + fout]       : 0.0f;
    float b = (k0 + 1 < 6) ? Wd1[(k0 + 1) * 128 + fout] : 0.0f;
    val = pack_f16_rne(a, b);
  } else if (off < OFF_WO) {              // L5: 128->256
    int rel = off - OFF_W5;
    int blk = rel >> 10, li = (rel >> 4) & 63, j2 = (rel >> 2) & 3;
    int mi = blk >> 2, ki = blk & 3;
    int fout = mi * 16 + (li & 15);
    int k0 = ki * 32 + (li >> 4) * 8 + j2 * 2;
    val = pack_f16_rne(Wd2[k0 * 256 + fout], Wd2[(k0 + 1) * 256 + fout]);
  } else if (off < OFF_B1) {
    val = __builtin_bit_cast(unsigned, Wo[(off - OFF_WO) >> 2]);
  } else if (off < OFF_B2) {
    val = __builtin_bit_cast(unsigned, b1[(off - OFF_B1) >> 2]);
  } else if (off < OFF_B3) {
    val = __builtin_bit_cast(unsigned, be1[(off - OFF_B2) >> 2]);
  } else if (off < OFF_B4) {
    int i = (off - OFF_B3) >> 2;
    float v = (i < 6) ? be2[i] : 0.0f;
    val = __builtin_bit_cast(unsigned, v);
  } else if (off < OFF_B5) {
    val = __builtin_bit_cast(unsigned, bd1[(off - OFF_B4) >> 2]);
  } else {
    val = __builtin_bit_cast(unsigned, bd2[(off - OFF_B5) >> 2]);
  }
  *(unsigned*)(g_img + off) = val;
}

// Fused layer: for each output k-tile (32 feats = mi pair 2ko,2ko+1), run the
// MFMAs, tanh+pack the C-frags, and IMMEDIATELY shuffle them into the next
// layer's B-operand frags. Only `bin` (KI tiles) + `bout` (grows to KO tiles)
// are live — never a full C-frag array.
template<int KO, int KI>
static __device__ __forceinline__ void layer_fused(const char* smem, int woff, int boff,
    const int (&bin)[2][KI][4], int (&bout)[2][KO][4],
    int ln, int q, int s1, int s2, bool qlo)
{
#pragma unroll
  for (int ko = 0; ko < KO; ++ko) {
    int tmp[2][2][2];   // [g][sub][reg]
#pragma unroll
    for (int sub = 0; sub < 2; ++sub) {
      int mi = 2 * ko + sub;
      f32x4 bias = *(const f32x4*)(smem + boff + mi * 64 + q * 16);
      f32x4 a0 = bias, a1 = bias;
#pragma unroll
      for (int ki = 0; ki < KI; ++ki) {
        H8 A;
        A.h = *(const half8*)(smem + woff + (mi * KI + ki) * 1024 + ln * 16);
        a0 = MFMA(A, bin[0][ki], a0);
        a1 = MFMA(A, bin[1][ki], a1);
      }
      tmp[0][sub][0] = pkrtz(tanh_f(a0[0]), tanh_f(a0[1]));
      tmp[0][sub][1] = pkrtz(tanh_f(a0[2]), tanh_f(a0[3]));
      tmp[1][sub][0] = pkrtz(tanh_f(a1[0]), tanh_f(a1[1]));
      tmp[1][sub][1] = pkrtz(tanh_f(a1[2]), tanh_f(a1[3]));
    }
#pragma unroll
    for (int g = 0; g < 2; ++g) {
      int x0 = __shfl(tmp[g][0][0], s1, 64), y0 = __shfl(tmp[g][1][0], s1, 64);
      int x1 = __shfl(tmp[g][0][1], s1, 64), y1 = __shfl(tmp[g][1][1], s1, 64);
      int x2 = __shfl(tmp[g][0][0], s2, 64), y2 = __shfl(tmp[g][1][0], s2, 64);
      int x3 = __shfl(tmp[g][0][1], s2, 64), y3 = __shfl(tmp[g][1][1], s2, 64);
      bout[g][ko][0] = qlo ? x0 : y0;
      bout[g][ko][1] = qlo ? x1 : y1;
      bout[g][ko][2] = qlo ? x2 : y2;
      bout[g][ko][3] = qlo ? x3 : y3;
    }
  }
}

__global__ __launch_bounds__(512)
__attribute__((amdgpu_waves_per_eu(2, 2)))   // LDS caps at 1 block/CU anyway; pin -> 256-VGPR budget, no spills
void gnn_main(const float* __restrict__ ea, float* __restrict__ out,
              const float* __restrict__ bo_p)
{
  __shared__ __align__(16) char smem[IMG_BYTES];
  const int tid = threadIdx.x;
  const int wv = tid >> 6, ln = tid & 63;

  // ---- stage weight image to LDS once per persistent block ----
#pragma unroll 1
  for (int r = 0; r < 19; ++r) {
    int cb = (r * 8 + wv) << 6;
    __builtin_amdgcn_global_load_lds(
        (const __attribute__((address_space(1))) void*)(g_img + (size_t)(cb + ln) * 16),
        (__attribute__((address_space(3))) void*)(smem + (size_t)cb * 16), 16, 0, 0);
  }
  if (wv == 0 && ln < 4) {
    __builtin_amdgcn_global_load_lds(
        (const __attribute__((address_space(1))) void*)(g_img + (size_t)(9728 + ln) * 16),
        (__attribute__((address_space(3))) void*)(smem + (size_t)9728 * 16), 16, 0, 0);
  }
  __syncthreads();

  const int q = ln >> 4, c = ln & 15;
  const bool qlo = (q < 2);
  const int s1 = ((q & 1) << 5) + c;
  const int s2 = s1 + 16;
  const float bo = *bo_p;

  const int NT = (N_NODES + 255) / 256;
#pragma unroll 1
  for (int t = blockIdx.x; t < NT; t += gridDim.x) {
    const int base = t * 256 + wv * 32;

    // ---- L1 input: edge_attr as X^T, f16 B-frags ----
    int nl = base + (q >> 1) * 16 + c;
    if (nl > N_NODES - 1) nl = N_NODES - 1;
    const f32x4* ea4 = (const f32x4*)ea;
    size_t eb = (size_t)nl * 4 + (size_t)((q & 1) * 2);
    f32x4 vlo = ea4[eb];
    f32x4 vhi = ea4[eb + 1];
    int p0 = pkrtz(vlo[0], vlo[1]), p1 = pkrtz(vlo[2], vlo[3]);
    int p2 = pkrtz(vhi[0], vhi[1]), p3 = pkrtz(vhi[2], vhi[3]);
    int bin1[2][1][4];
    bin1[0][0][0] = qlo ? p0 : 0; bin1[0][0][1] = qlo ? p1 : 0;
    bin1[0][0][2] = qlo ? p2 : 0; bin1[0][0][3] = qlo ? p3 : 0;
    int sh = (ln + 32) & 63;
    int r0 = __shfl(p0, sh, 64), r1 = __shfl(p1, sh, 64);
    int r2 = __shfl(p2, sh, 64), r3 = __shfl(p3, sh, 64);
    bin1[1][0][0] = qlo ? r0 : 0; bin1[1][0][1] = qlo ? r1 : 0;
    bin1[1][0][2] = qlo ? r2 : 0; bin1[1][0][3] = qlo ? r3 : 0;

    // ---- L1: 16 -> 256, fused straight into L2 B-frags ----
    int bin2[2][8][4];
#pragma unroll
    for (int ko = 0; ko < 8; ++ko) {
      int tmp[2][2][2];
#pragma unroll
      for (int sub = 0; sub < 2; ++sub) {
        int mi = 2 * ko + sub;
        f32x4 bias = *(const f32x4*)(smem + OFF_B1 + mi * 64 + q * 16);
        H8 A;
        A.h = *(const half8*)(smem + OFF_W1 + mi * 512 + (ln & 31) * 16);
        if (!qlo) { A.i[0] = 0; A.i[1] = 0; A.i[2] = 0; A.i[3] = 0; }  // K-pad rows
        f32x4 a0 = bias, a1 = bias;
        a0 = MFMA(A, bin1[0][0], a0);
        a1 = MFMA(A, bin1[1][0], a1);
        tmp[0][sub][0] = pkrtz(tanh_f(a0[0]), tanh_f(a0[1]));
        tmp[0][sub][1] = pkrtz(tanh_f(a0[2]), tanh_f(a0[3]));
        tmp[1][sub][0] = pkrtz(tanh_f(a1[0]), tanh_f(a1[1]));
        tmp[1][sub][1] = pkrtz(tanh_f(a1[2]), tanh_f(a1[3]));
      }
#pragma unroll
      for (int g = 0; g < 2; ++g) {
        int x0 = __shfl(tmp[g][0][0], s1, 64), y0 = __shfl(tmp[g][1][0], s1, 64);
        int x1 = __shfl(tmp[g][0][1], s1, 64), y1 = __shfl(tmp[g][1][1], s1, 64);
        int x2 = __shfl(tmp[g][0][0], s2, 64), y2 = __shfl(tmp[g][1][0], s2, 64);
        int x3 = __shfl(tmp[g][0][1], s2, 64), y3 = __shfl(tmp[g][1][1], s2, 64);
        bin2[g][ko][0] = qlo ? x0 : y0;
        bin2[g][ko][1] = qlo ? x1 : y1;
        bin2[g][ko][2] = qlo ? x2 : y2;
        bin2[g][ko][3] = qlo ? x3 : y3;
      }
    }

    // ---- L2: 256 -> 128 -> L3 B-frags ----
    int bin3[2][4][4];
    layer_fused<4, 8>(smem, OFF_W2, OFF_B2, bin2, bin3, ln, q, s1, s2, qlo);

    // ---- L3: 128 -> 6 (one mi tile; rows 6..15 exactly 0) ----
    int pk3[2][2];
    {
#pragma unroll
      for (int g2 = 0; g2 < 1; ++g2) {}  // (keep structure simple)
      f32x4 bias = *(const f32x4*)(smem + OFF_B3 + q * 16);
      f32x4 a0 = bias, a1 = bias;
#pragma unroll
      for (int ki = 0; ki < 4; ++ki) {
        H8 A;
        A.h = *(const half8*)(smem + OFF_W3 + ki * 1024 + ln * 16);
        a0 = MFMA(A, bin3[0][ki], a0);
        a1 = MFMA(A, bin3[1][ki], a1);
      }
      pk3[0][0] = pkrtz(tanh_f(a0[0]), tanh_f(a0[1]));
      pk3[0][1] = pkrtz(tanh_f(a0[2]), tanh_f(a0[3]));
      pk3[1][0] = pkrtz(tanh_f(a1[0]), tanh_f(a1[1]));
      pk3[1][1] = pkrtz(tanh_f(a1[2]), tanh_f(a1[3]));
    }

    // ---- L4 input: 6 feats (K padded to 32; k>=16 lanes zeroed) ----
    int bin4[2][1][4];
#pragma unroll
    for (int g = 0; g < 2; ++g) {
      int a0s = __shfl(pk3[g][0], s1, 64), a1s = __shfl(pk3[g][1], s1, 64);
      int a2s = __shfl(pk3[g][0], s2, 64), a3s = __shfl(pk3[g][1], s2, 64);
      bin4[g][0][0] = qlo ? a0s : 0;
      bin4[g][0][1] = qlo ? a1s : 0;
      bin4[g][0][2] = qlo ? a2s : 0;
      bin4[g][0][3] = qlo ? a3s : 0;
    }

    // ---- L4: 6 -> 128 -> L5 B-frags ----
    int bin5[2][4][4];
    layer_fused<4, 1>(smem, OFF_W4, OFF_B4, bin4, bin5, ln, q, s1, s2, qlo);

    // ---- L5: 128 -> 256 fused with L6: out = sigmoid(tanh(d).Wo + bo) ----
    float part0 = 0.0f, part1 = 0.0f;
#pragma unroll
    for (int mi = 0; mi < 16; ++mi) {
      f32x4 bias = *(const f32x4*)(smem + OFF_B5 + mi * 64 + q * 16);
      f32x4 a0 = bias, a1 = bias;
#pragma unroll
      for (int ki = 0; ki < 4; ++ki) {
        H8 A;
        A.h = *(const half8*)(smem + OFF_W5 + (mi * 4 + ki) * 1024 + ln * 16);
        a0 = MFMA(A, bin5[0][ki], a0);
        a1 = MFMA(A, bin5[1][ki], a1);
      }
      f32x4 wo = *(const f32x4*)(smem + OFF_WO + mi * 64 + q * 16);
      part0 += tanh_f(a0[0]) * wo[0] + tanh_f(a0[1]) * wo[1]
             + tanh_f(a0[2]) * wo[2] + tanh_f(a0[3]) * wo[3];
      part1 += tanh_f(a1[0]) * wo[0] + tanh_f(a1[1]) * wo[1]
             + tanh_f(a1[2]) * wo[2] + tanh_f(a1[3]) * wo[3];
    }
    part0 += __shfl_xor(part0, 16, 64); part0 += __shfl_xor(part0, 32, 64);
    part1 += __shfl_xor(part1, 16, 64); part1 += __shfl_xor(part1, 32, 64);
    if (q < 2) {
      int node = base + q * 16 + c;
      if (node < N_NODES) {
        float v = ((q == 0) ? part0 : part1) + bo;
        out[node] = sigmoid_f(v);
      }
    }
  }
}

extern "C" void kernel_launch(void* const* d_in, const int* in_sizes, int n_in,
                              void* d_out, int out_size, void* d_ws, size_t ws_size,
                              hipStream_t stream) {
  (void)in_sizes; (void)n_in; (void)d_ws; (void)ws_size; (void)out_size;
  const float* ea  = (const float*)d_in[2];
  const float* W1  = (const float*)d_in[3];
  const float* b1  = (const float*)d_in[4];
  const float* We1 = (const float*)d_in[5];
  const float* be1 = (const float*)d_in[6];
  const float* We2 = (const float*)d_in[7];
  const float* be2 = (const float*)d_in[8];
  const float* Wd1 = (const float*)d_in[9];
  const float* bd1 = (const float*)d_in[10];
  const float* Wd2 = (const float*)d_in[11];
  const float* bd2 = (const float*)d_in[12];
  const float* Wo  = (const float*)d_in[13];
  const float* bo  = (const float*)d_in[14];

  gnn_prep<<<dim3((IMG_BYTES / 4 + 255) / 256), dim3(256), 0, stream>>>(
      W1, b1, We1, be1, We2, be2, Wd1, bd1, Wd2, bd2, Wo);
  gnn_main<<<dim3(256), dim3(512), 0, stream>>>(ea, (float*)d_out, bo);
}

// Round 4
// 970.796 us; speedup vs baseline: 1.0150x; 1.0150x over previous
//
#include <hip/hip_runtime.h>

// Per-node MLP 16->256->128->6->128->256->1 (tanh...sigmoid) on
// edge_attr.reshape(500000,16). x / edge_index are dead inputs.
//
// f16 MFMA 16x16x32, feature-major activations. Weights pre-fragmented to
// A-operand layout in g_img; each block stages them to LDS once
// (global_load_lds w=16) and pushes 32 nodes/wave through all layers.
// R4: R2/R3 burned 1.9 GB/dispatch of scratch traffic — the activation
// B-fragment ARRAYS were never promoted to registers (address-taken int*
// + union punning defeated SROA; VGPR_Count stuck at 128). This version has
// ZERO aggregates in the hot loop: every fragment is a named ext_vector
// value, moved only by value / __builtin_bit_cast.

#define N_NODES 500000

// ---- weight-image layout (bytes). All offsets 16B-aligned. ----
#define OFF_W1 0        // 16 blocks x 512B (L1: K=16 -> lanes 0..31 hold data)
#define OFF_W2 8192     // 64 blocks x 1KB  (L2: 256->128, mi*8+ki)
#define OFF_W3 73728    // 4  blocks x 1KB  (L3: 128->16(6 valid), ki)
#define OFF_W4 77824    // 8  blocks x 1KB  (L4: 6(pad32)->128, mi)
#define OFF_W5 86016    // 64 blocks x 1KB  (L5: 128->256, mi*4+ki)
#define OFF_WO 151552   // 256 f32 (output weights)
#define OFF_B1 152576   // 256 f32
#define OFF_B2 153600   // 128 f32
#define OFF_B3 154112   // 16  f32 (6 valid, rest 0)
#define OFF_B4 154176   // 128 f32
#define OFF_B5 154688   // 256 f32
#define IMG_BYTES 155712
// 16B chunks: 9732 = 19 rounds x 8 waves x 64 lanes + 4 tail chunks

typedef _Float16 half8  __attribute__((ext_vector_type(8)));
typedef __fp16   pk16x2 __attribute__((ext_vector_type(2)));
typedef float    f32x4  __attribute__((ext_vector_type(4)));
typedef int      int4v  __attribute__((ext_vector_type(4)));

__device__ __align__(16) char g_img[IMG_BYTES];

static __device__ __forceinline__ unsigned pack_f16_rne(float a, float b) {
  _Float16 ha = (_Float16)a, hb = (_Float16)b;
  unsigned short ua = __builtin_bit_cast(unsigned short, ha);
  unsigned short ub = __builtin_bit_cast(unsigned short, hb);
  return (unsigned)ua | ((unsigned)ub << 16);
}

static __device__ __forceinline__ int pkrtz(float a, float b) {
  pk16x2 h = __builtin_amdgcn_cvt_pkrtz(a, b);
  return __builtin_bit_cast(int, h);
}

static __device__ __forceinline__ float tanh_f(float x) {
  float e = __builtin_amdgcn_exp2f(x * 2.8853900817779268f);
  float r = __builtin_amdgcn_rcpf(e + 1.0f);
  return __builtin_fmaf(-2.0f, r, 1.0f);
}

static __device__ __forceinline__ float sigmoid_f(float x) {
  float e = __builtin_amdgcn_exp2f(x * -1.4426950408889634f);
  return __builtin_amdgcn_rcpf(1.0f + e);
}

static __device__ __forceinline__ f32x4 mfma16(half8 a, int4v b, f32x4 c) {
  return __builtin_amdgcn_mfma_f32_16x16x32_f16(a, __builtin_bit_cast(half8, b), c, 0, 0, 0);
}
static __device__ __forceinline__ half8 lda(const char* smem, int off) {
  return *(const half8*)(smem + off);
}
static __device__ __forceinline__ f32x4 ldf4(const char* smem, int off) {
  return *(const f32x4*)(smem + off);
}

struct PK2 { int lo, hi; };
static __device__ __forceinline__ PK2 tp(f32x4 a) {
  PK2 p;
  p.lo = pkrtz(tanh_f(a.x), tanh_f(a.y));
  p.hi = pkrtz(tanh_f(a.z), tanh_f(a.w));
  return p;
}

// C-frag pair (even mi = k 0..15, odd mi = k 16..31) -> next-layer B-frag.
static __device__ __forceinline__ int4v xform(PK2 e, PK2 o, int s1, int s2, bool qlo) {
  int x0 = __shfl(e.lo, s1, 64), y0 = __shfl(o.lo, s1, 64);
  int x1 = __shfl(e.hi, s1, 64), y1 = __shfl(o.hi, s1, 64);
  int x2 = __shfl(e.lo, s2, 64), y2 = __shfl(o.lo, s2, 64);
  int x3 = __shfl(e.hi, s2, 64), y3 = __shfl(o.hi, s2, 64);
  int4v r;
  r.x = qlo ? x0 : y0;
  r.y = qlo ? x1 : y1;
  r.z = qlo ? x2 : y2;
  r.w = qlo ? x3 : y3;
  return r;
}

// ---------------- prep: gather/transpose/convert weights into g_img ----------------
// A-fragment layout per 1KB block (mi,ki): lane L holds 16B = 8 f16 =
// W^T[16*mi + (L&15)][32*ki + 8*(L>>4) + 0..7]
__global__ void gnn_prep(const float* __restrict__ W1,  const float* __restrict__ b1,
                         const float* __restrict__ We1, const float* __restrict__ be1,
                         const float* __restrict__ We2, const float* __restrict__ be2,
                         const float* __restrict__ Wd1, const float* __restrict__ bd1,
                         const float* __restrict__ Wd2, const float* __restrict__ bd2,
                         const float* __restrict__ Wo)
{
  int t = blockIdx.x * 256 + threadIdx.x;
  int off = t * 4;
  if (off >= IMG_BYTES) return;
  unsigned val;
  if (off < OFF_W2) {                     // L1 (K=16): 512B half-blocks
    int rel = off;
    int mi = rel >> 9, li = (rel >> 4) & 31, j2 = (rel >> 2) & 3;
    int fout = mi * 16 + (li & 15);
    int k0 = (li >> 4) * 8 + j2 * 2;
    val = pack_f16_rne(W1[k0 * 256 + fout], W1[(k0 + 1) * 256 + fout]);
  } else if (off < OFF_W3) {              // L2: 256->128
    int rel = off - OFF_W2;
    int blk = rel >> 10, li = (rel >> 4) & 63, j2 = (rel >> 2) & 3;
    int mi = blk >> 3, ki = blk & 7;
    int fout = mi * 16 + (li & 15);
    int k0 = ki * 32 + (li >> 4) * 8 + j2 * 2;
    val = pack_f16_rne(We1[k0 * 128 + fout], We1[(k0 + 1) * 128 + fout]);
  } else if (off < OFF_W4) {              // L3: 128->6 (fout padded to 16)
    int rel = off - OFF_W3;
    int ki = rel >> 10, li = (rel >> 4) & 63, j2 = (rel >> 2) & 3;
    int fo = li & 15;
    int k0 = ki * 32 + (li >> 4) * 8 + j2 * 2;
    float a = (fo < 6) ? We2[k0 * 6 + fo] : 0.0f;
    float b = (fo < 6) ? We2[(k0 + 1) * 6 + fo] : 0.0f;
    val = pack_f16_rne(a, b);
  } else if (off < OFF_W5) {              // L4: 6->128 (K padded to 32)
    int rel = off - OFF_W4;
    int mi = rel >> 10, li = (rel >> 4) & 63, j2 = (rel >> 2) & 3;
    int fout = mi * 16 + (li & 15);
    int k0 = (li >> 4) * 8 + j2 * 2;
    float a = (k0 < 6)     ? Wd1[k0 * 128 + fout]       : 0.0f;
    float b = (k0 + 1 < 6) ? Wd1[(k0 + 1) * 128 + fout] : 0.0f;
    val = pack_f16_rne(a, b);
  } else if (off < OFF_WO) {              // L5: 128->256
    int rel = off - OFF_W5;
    int blk = rel >> 10, li = (rel >> 4) & 63, j2 = (rel >> 2) & 3;
    int mi = blk >> 2, ki = blk & 3;
    int fout = mi * 16 + (li & 15);
    int k0 = ki * 32 + (li >> 4) * 8 + j2 * 2;
    val = pack_f16_rne(Wd2[k0 * 256 + fout], Wd2[(k0 + 1) * 256 + fout]);
  } else if (off < OFF_B1) {
    val = __builtin_bit_cast(unsigned, Wo[(off - OFF_WO) >> 2]);
  } else if (off < OFF_B2) {
    val = __builtin_bit_cast(unsigned, b1[(off - OFF_B1) >> 2]);
  } else if (off < OFF_B3) {
    val = __builtin_bit_cast(unsigned, be1[(off - OFF_B2) >> 2]);
  } else if (off < OFF_B4) {
    int i = (off - OFF_B3) >> 2;
    float v = (i < 6) ? be2[i] : 0.0f;
    val = __builtin_bit_cast(unsigned, v);
  } else if (off < OFF_B5) {
    val = __builtin_bit_cast(unsigned, bd1[(off - OFF_B4) >> 2]);
  } else {
    val = __builtin_bit_cast(unsigned, bd2[(off - OFF_B5) >> 2]);
  }
  *(unsigned*)(g_img + off) = val;
}

// ---- macros over NAMED fragment values (no arrays anywhere) ----

#define L1_PAIR(KO, OUT_G0, OUT_G1) do {                                   \
    half8 Ae = lda(smem, OFF_W1 + (2*(KO))*512 + (ln & 31)*16);            \
    half8 Ao = lda(smem, OFF_W1 + (2*(KO)+1)*512 + (ln & 31)*16);          \
    if (!qlo) { Ae = h8z; Ao = h8z; }                                      \
    f32x4 be_ = ldf4(smem, OFF_B1 + (2*(KO))*64 + q*16);                   \
    f32x4 bo_ = ldf4(smem, OFF_B1 + (2*(KO)+1)*64 + q*16);                 \
    f32x4 ae0 = mfma16(Ae, b1g0, be_);                                     \
    f32x4 ae1 = mfma16(Ae, b1g1, be_);                                     \
    f32x4 ao0 = mfma16(Ao, b1g0, bo_);                                     \
    f32x4 ao1 = mfma16(Ao, b1g1, bo_);                                     \
    PK2 pe0 = tp(ae0), po0 = tp(ao0), pe1 = tp(ae1), po1 = tp(ao1);        \
    OUT_G0 = xform(pe0, po0, s1, s2, qlo);                                 \
    OUT_G1 = xform(pe1, po1, s1, s2, qlo);                                 \
  } while (0)

#define L2_MI(MI, ACC0, ACC1) do {                                                            \
    f32x4 bb = ldf4(smem, OFF_B2 + (MI)*64 + q*16);                                           \
    ACC0 = bb; ACC1 = bb;                                                                     \
    half8 A;                                                                                  \
    A = lda(smem, OFF_W2 + ((MI)*8+0)*1024 + ln*16); ACC0 = mfma16(A, c2g0_0, ACC0); ACC1 = mfma16(A, c2g1_0, ACC1); \
    A = lda(smem, OFF_W2 + ((MI)*8+1)*1024 + ln*16); ACC0 = mfma16(A, c2g0_1, ACC0); ACC1 = mfma16(A, c2g1_1, ACC1); \
    A = lda(smem, OFF_W2 + ((MI)*8+2)*1024 + ln*16); ACC0 = mfma16(A, c2g0_2, ACC0); ACC1 = mfma16(A, c2g1_2, ACC1); \
    A = lda(smem, OFF_W2 + ((MI)*8+3)*1024 + ln*16); ACC0 = mfma16(A, c2g0_3, ACC0); ACC1 = mfma16(A, c2g1_3, ACC1); \
    A = lda(smem, OFF_W2 + ((MI)*8+4)*1024 + ln*16); ACC0 = mfma16(A, c2g0_4, ACC0); ACC1 = mfma16(A, c2g1_4, ACC1); \
    A = lda(smem, OFF_W2 + ((MI)*8+5)*1024 + ln*16); ACC0 = mfma16(A, c2g0_5, ACC0); ACC1 = mfma16(A, c2g1_5, ACC1); \
    A = lda(smem, OFF_W2 + ((MI)*8+6)*1024 + ln*16); ACC0 = mfma16(A, c2g0_6, ACC0); ACC1 = mfma16(A, c2g1_6, ACC1); \
    A = lda(smem, OFF_W2 + ((MI)*8+7)*1024 + ln*16); ACC0 = mfma16(A, c2g0_7, ACC0); ACC1 = mfma16(A, c2g1_7, ACC1); \
  } while (0)

#define L2_PAIR(KO, OUT_G0, OUT_G1) do {                                   \
    f32x4 ve0, ve1, vo0, vo1;                                              \
    L2_MI(2*(KO),   ve0, ve1);                                             \
    L2_MI(2*(KO)+1, vo0, vo1);                                             \
    PK2 pe0 = tp(ve0), po0 = tp(vo0), pe1 = tp(ve1), po1 = tp(vo1);        \
    OUT_G0 = xform(pe0, po0, s1, s2, qlo);                                 \
    OUT_G1 = xform(pe1, po1, s1, s2, qlo);                                 \
  } while (0)

#define L4_MI(MI, ACC0, ACC1) do {                                         \
    f32x4 bb = ldf4(smem, OFF_B4 + (MI)*64 + q*16);                        \
    half8 A = lda(smem, OFF_W4 + (MI)*1024 + ln*16);                       \
    ACC0 = mfma16(A, b4g0, bb);                                            \
    ACC1 = mfma16(A, b4g1, bb);                                            \
  } while (0)

#define L4_PAIR(KO, OUT_G0, OUT_G1) do {                                   \
    f32x4 ve0, ve1, vo0, vo1;                                              \
    L4_MI(2*(KO),   ve0, ve1);                                             \
    L4_MI(2*(KO)+1, vo0, vo1);                                             \
    PK2 pe0 = tp(ve0), po0 = tp(vo0), pe1 = tp(ve1), po1 = tp(vo1);        \
    OUT_G0 = xform(pe0, po0, s1, s2, qlo);                                 \
    OUT_G1 = xform(pe1, po1, s1, s2, qlo);                                 \
  } while (0)

#define L5_MI(MI) do {                                                                        \
    f32x4 bb = ldf4(smem, OFF_B5 + (MI)*64 + q*16);                                           \
    f32x4 a0 = bb, a1 = bb;                                                                   \
    half8 A;                                                                                  \
    A = lda(smem, OFF_W5 + ((MI)*4+0)*1024 + ln*16); a0 = mfma16(A, c5g0_0, a0); a1 = mfma16(A, c5g1_0, a1); \
    A = lda(smem, OFF_W5 + ((MI)*4+1)*1024 + ln*16); a0 = mfma16(A, c5g0_1, a0); a1 = mfma16(A, c5g1_1, a1); \
    A = lda(smem, OFF_W5 + ((MI)*4+2)*1024 + ln*16); a0 = mfma16(A, c5g0_2, a0); a1 = mfma16(A, c5g1_2, a1); \
    A = lda(smem, OFF_W5 + ((MI)*4+3)*1024 + ln*16); a0 = mfma16(A, c5g0_3, a0); a1 = mfma16(A, c5g1_3, a1); \
    f32x4 wo = ldf4(smem, OFF_WO + (MI)*64 + q*16);                                           \
    part0 += tanh_f(a0.x)*wo.x + tanh_f(a0.y)*wo.y + tanh_f(a0.z)*wo.z + tanh_f(a0.w)*wo.w;   \
    part1 += tanh_f(a1.x)*wo.x + tanh_f(a1.y)*wo.y + tanh_f(a1.z)*wo.z + tanh_f(a1.w)*wo.w;   \
  } while (0)

__global__ __launch_bounds__(512, 2)
void gnn_main(const float* __restrict__ ea, float* __restrict__ out,
              const float* __restrict__ bo_p)
{
  __shared__ __align__(16) char smem[IMG_BYTES];
  const int tid = threadIdx.x;
  const int wv = tid >> 6, ln = tid & 63;

  // ---- stage weight image to LDS once per persistent block ----
#pragma unroll 1
  for (int r = 0; r < 19; ++r) {
    int cb = (r * 8 + wv) << 6;
    __builtin_amdgcn_global_load_lds(
        (const __attribute__((address_space(1))) void*)(g_img + (size_t)(cb + ln) * 16),
        (__attribute__((address_space(3))) void*)(smem + (size_t)cb * 16), 16, 0, 0);
  }
  if (wv == 0 && ln < 4) {
    __builtin_amdgcn_global_load_lds(
        (const __attribute__((address_space(1))) void*)(g_img + (size_t)(9728 + ln) * 16),
        (__attribute__((address_space(3))) void*)(smem + (size_t)9728 * 16), 16, 0, 0);
  }
  __syncthreads();

  const int q = ln >> 4, c = ln & 15;
  const bool qlo = (q < 2);
  const int s1 = ((q & 1) << 5) + c;
  const int s2 = s1 + 16;
  const float bo = *bo_p;

  const int4v zi4 = {0, 0, 0, 0};
  const half8 h8z = __builtin_bit_cast(half8, zi4);

  const int NT = (N_NODES + 255) / 256;
#pragma unroll 1
  for (int t = blockIdx.x; t < NT; t += gridDim.x) {
    const int base = t * 256 + wv * 32;

    // ---- L1 input: edge_attr as X^T, f16 B-frags (named values) ----
    int nl = base + (q >> 1) * 16 + c;
    if (nl > N_NODES - 1) nl = N_NODES - 1;
    const f32x4* ea4 = (const f32x4*)ea;
    size_t eb = (size_t)nl * 4 + (size_t)((q & 1) * 2);
    f32x4 vlo = ea4[eb];
    f32x4 vhi = ea4[eb + 1];
    int p0 = pkrtz(vlo.x, vlo.y), p1 = pkrtz(vlo.z, vlo.w);
    int p2 = pkrtz(vhi.x, vhi.y), p3 = pkrtz(vhi.z, vhi.w);
    int4v b1g0, b1g1;
    b1g0.x = qlo ? p0 : 0; b1g0.y = qlo ? p1 : 0;
    b1g0.z = qlo ? p2 : 0; b1g0.w = qlo ? p3 : 0;
    int sh = (ln + 32) & 63;
    int r0 = __shfl(p0, sh, 64), r1 = __shfl(p1, sh, 64);
    int r2 = __shfl(p2, sh, 64), r3 = __shfl(p3, sh, 64);
    b1g1.x = qlo ? r0 : 0; b1g1.y = qlo ? r1 : 0;
    b1g1.z = qlo ? r2 : 0; b1g1.w = qlo ? r3 : 0;

    // ---- L1: 16 -> 256 -> L2 B-frags ----
    int4v c2g0_0, c2g0_1, c2g0_2, c2g0_3, c2g0_4, c2g0_5, c2g0_6, c2g0_7;
    int4v c2g1_0, c2g1_1, c2g1_2, c2g1_3, c2g1_4, c2g1_5, c2g1_6, c2g1_7;
    L1_PAIR(0, c2g0_0, c2g1_0);
    L1_PAIR(1, c2g0_1, c2g1_1);
    L1_PAIR(2, c2g0_2, c2g1_2);
    L1_PAIR(3, c2g0_3, c2g1_3);
    L1_PAIR(4, c2g0_4, c2g1_4);
    L1_PAIR(5, c2g0_5, c2g1_5);
    L1_PAIR(6, c2g0_6, c2g1_6);
    L1_PAIR(7, c2g0_7, c2g1_7);

    // ---- L2: 256 -> 128 -> L3 B-frags ----
    int4v c3g0_0, c3g0_1, c3g0_2, c3g0_3;
    int4v c3g1_0, c3g1_1, c3g1_2, c3g1_3;
    L2_PAIR(0, c3g0_0, c3g1_0);
    L2_PAIR(1, c3g0_1, c3g1_1);
    L2_PAIR(2, c3g0_2, c3g1_2);
    L2_PAIR(3, c3g0_3, c3g1_3);

    // ---- L3: 128 -> 6 (single mi tile; rows 6..15 exactly 0) ----
    PK2 p3g0, p3g1;
    {
      f32x4 bb3 = ldf4(smem, OFF_B3 + q * 16);
      f32x4 z0 = bb3, z1 = bb3;
      half8 A;
      A = lda(smem, OFF_W3 + 0 * 1024 + ln * 16); z0 = mfma16(A, c3g0_0, z0); z1 = mfma16(A, c3g1_0, z1);
      A = lda(smem, OFF_W3 + 1 * 1024 + ln * 16); z0 = mfma16(A, c3g0_1, z0); z1 = mfma16(A, c3g1_1, z1);
      A = lda(smem, OFF_W3 + 2 * 1024 + ln * 16); z0 = mfma16(A, c3g0_2, z0); z1 = mfma16(A, c3g1_2, z1);
      A = lda(smem, OFF_W3 + 3 * 1024 + ln * 16); z0 = mfma16(A, c3g0_3, z0); z1 = mfma16(A, c3g1_3, z1);
      p3g0 = tp(z0);
      p3g1 = tp(z1);
    }

    // ---- L4 input: 6 feats (K padded to 32; k>=16 lanes zeroed) ----
    int4v b4g0, b4g1;
    {
      int a0 = __shfl(p3g0.lo, s1, 64), a1 = __shfl(p3g0.hi, s1, 64);
      int a2 = __shfl(p3g0.lo, s2, 64), a3 = __shfl(p3g0.hi, s2, 64);
      b4g0.x = qlo ? a0 : 0; b4g0.y = qlo ? a1 : 0;
      b4g0.z = qlo ? a2 : 0; b4g0.w = qlo ? a3 : 0;
      int d0 = __shfl(p3g1.lo, s1, 64), d1 = __shfl(p3g1.hi, s1, 64);
      int d2 = __shfl(p3g1.lo, s2, 64), d3 = __shfl(p3g1.hi, s2, 64);
      b4g1.x = qlo ? d0 : 0; b4g1.y = qlo ? d1 : 0;
      b4g1.z = qlo ? d2 : 0; b4g1.w = qlo ? d3 : 0;
    }

    // ---- L4: 6 -> 128 -> L5 B-frags ----
    int4v c5g0_0, c5g0_1, c5g0_2, c5g0_3;
    int4v c5g1_0, c5g1_1, c5g1_2, c5g1_3;
    L4_PAIR(0, c5g0_0, c5g1_0);
    L4_PAIR(1, c5g0_1, c5g1_1);
    L4_PAIR(2, c5g0_2, c5g1_2);
    L4_PAIR(3, c5g0_3, c5g1_3);

    // ---- L5: 128 -> 256 fused with L6: out = sigmoid(tanh(d).Wo + bo) ----
    float part0 = 0.0f, part1 = 0.0f;
    L5_MI(0);  L5_MI(1);  L5_MI(2);  L5_MI(3);
    L5_MI(4);  L5_MI(5);  L5_MI(6);  L5_MI(7);
    L5_MI(8);  L5_MI(9);  L5_MI(10); L5_MI(11);
    L5_MI(12); L5_MI(13); L5_MI(14); L5_MI(15);

    part0 += __shfl_xor(part0, 16, 64); part0 += __shfl_xor(part0, 32, 64);
    part1 += __shfl_xor(part1, 16, 64); part1 += __shfl_xor(part1, 32, 64);
    if (q < 2) {
      int node = base + q * 16 + c;
      if (node < N_NODES) {
        float v = ((q == 0) ? part0 : part1) + bo;
        out[node] = sigmoid_f(v);
      }
    }
  }
}

extern "C" void kernel_launch(void* const* d_in, const int* in_sizes, int n_in,
                              void* d_out, int out_size, void* d_ws, size_t ws_size,
                              hipStream_t stream) {
  (void)in_sizes; (void)n_in; (void)d_ws; (void)ws_size; (void)out_size;
  const float* ea  = (const float*)d_in[2];
  const float* W1  = (const float*)d_in[3];
  const float* b1  = (const float*)d_in[4];
  const float* We1 = (const float*)d_in[5];
  const float* be1 = (const float*)d_in[6];
  const float* We2 = (const float*)d_in[7];
  const float* be2 = (const float*)d_in[8];
  const float* Wd1 = (const float*)d_in[9];
  const float* bd1 = (const float*)d_in[10];
  const float* Wd2 = (const float*)d_in[11];
  const float* bd2 = (const float*)d_in[12];
  const float* Wo  = (const float*)d_in[13];
  const float* bo  = (const float*)d_in[14];

  gnn_prep<<<dim3((IMG_BYTES / 4 + 255) / 256), dim3(256), 0, stream>>>(
      W1, b1, We1, be1, We2, be2, Wd1, bd1, Wd2, bd2, Wo);
  gnn_main<<<dim3(256), dim3(512), 0, stream>>>(ea, (float*)d_out, bo);
}

// Round 5
// 262.017 us; speedup vs baseline: 3.7607x; 3.7051x over previous
//
#include <hip/hip_runtime.h>

// Per-node MLP 16->256->128->6->128->256->1 (tanh...sigmoid) on
// edge_attr.reshape(500000,16). x / edge_index are dead inputs.
//
// R5: R2-R4 all burned ~1.9GB/dispatch of scratch traffic (B-fragments
// spilled; VGPR_Count pinned at 128 in every variant). Fix: split into two
// kernels at the 6-wide bottleneck (z -> d_ws), halving LDS (2 blocks/CU)
// and per-kernel live sets; sched_barrier(0) fences between MFMA chunks stop
// the scheduler from hoisting all ds_reads and blowing the register budget.

#define N_NODES 500000

// ---- weight-image layout in g_img (bytes) ----
#define OFF_W1 0        // 16 x 512B  (L1: K=16)
#define OFF_W2 8192     // 64 x 1KB   (L2: 256->128, mi*8+ki)
#define OFF_W3 73728    // 4  x 1KB   (L3: 128->16(6 valid), ki)
#define OFF_W4 77824    // 8  x 1KB   (L4: 6(pad32)->128, mi)
#define OFF_W5 86016    // 64 x 1KB   (L5: 128->256, mi*4+ki)
#define OFF_WO 151552   // 256 f32
#define OFF_B1 152576   // 256 f32
#define OFF_B2 153600   // 128 f32
#define OFF_B3 154112   // 16 f32 (6 valid)
#define OFF_B4 154176   // 128 f32
#define OFF_B5 154688   // 256 f32
#define IMG_BYTES 155712
#define IMG_ALLOC 156672   // padded: K2 staging tail reads past IMG_BYTES

// ---- K1 LDS: [W1 W2 W3][B1 B2 B3] ----
#define K1_LDS   79872     // 4992 chunks of 16B (4864 weights + 128 bias/pad)
#define K1_B1    77824
#define K1_B2    78848
#define K1_B3    79360
// ---- K2 LDS: [W4][W5][WO][B4 B5] ----
#define K2_LDS   76800     // 4800 chunks (512 + 4160 + 128 bias/pad)
#define K2_W4    0
#define K2_W5    8192
#define K2_WO    73728
#define K2_B4    74752
#define K2_B5    75264

typedef _Float16 half8  __attribute__((ext_vector_type(8)));
typedef __fp16   pk16x2 __attribute__((ext_vector_type(2)));
typedef float    f32x4  __attribute__((ext_vector_type(4)));
typedef int      int4v  __attribute__((ext_vector_type(4)));

__device__ __align__(16) char g_img[IMG_ALLOC];

static __device__ __forceinline__ unsigned pack_f16_rne(float a, float b) {
  _Float16 ha = (_Float16)a, hb = (_Float16)b;
  unsigned short ua = __builtin_bit_cast(unsigned short, ha);
  unsigned short ub = __builtin_bit_cast(unsigned short, hb);
  return (unsigned)ua | ((unsigned)ub << 16);
}
static __device__ __forceinline__ int pkrtz(float a, float b) {
  pk16x2 h = __builtin_amdgcn_cvt_pkrtz(a, b);
  return __builtin_bit_cast(int, h);
}
static __device__ __forceinline__ float tanh_f(float x) {
  float e = __builtin_amdgcn_exp2f(x * 2.8853900817779268f);
  float r = __builtin_amdgcn_rcpf(e + 1.0f);
  return __builtin_fmaf(-2.0f, r, 1.0f);
}
static __device__ __forceinline__ float sigmoid_f(float x) {
  float e = __builtin_amdgcn_exp2f(x * -1.4426950408889634f);
  return __builtin_amdgcn_rcpf(1.0f + e);
}
static __device__ __forceinline__ f32x4 mfma16(half8 a, int4v b, f32x4 c) {
  return __builtin_amdgcn_mfma_f32_16x16x32_f16(a, __builtin_bit_cast(half8, b), c, 0, 0, 0);
}
static __device__ __forceinline__ half8 lda(const char* smem, int off) {
  return *(const half8*)(smem + off);
}
static __device__ __forceinline__ f32x4 ldf4(const char* smem, int off) {
  return *(const f32x4*)(smem + off);
}
#define FENCE() __builtin_amdgcn_sched_barrier(0)

struct PK2 { int lo, hi; };
static __device__ __forceinline__ PK2 tp(f32x4 a) {
  PK2 p;
  p.lo = pkrtz(tanh_f(a.x), tanh_f(a.y));
  p.hi = pkrtz(tanh_f(a.z), tanh_f(a.w));
  return p;
}
// C-frag pair (even mi = k 0..15, odd mi = k 16..31) -> next-layer B-frag.
static __device__ __forceinline__ int4v xform(PK2 e, PK2 o, int s1, int s2, bool qlo) {
  int x0 = __shfl(e.lo, s1, 64), y0 = __shfl(o.lo, s1, 64);
  int x1 = __shfl(e.hi, s1, 64), y1 = __shfl(o.hi, s1, 64);
  int x2 = __shfl(e.lo, s2, 64), y2 = __shfl(o.lo, s2, 64);
  int x3 = __shfl(e.hi, s2, 64), y3 = __shfl(o.hi, s2, 64);
  int4v r;
  r.x = qlo ? x0 : y0;  r.y = qlo ? x1 : y1;
  r.z = qlo ? x2 : y2;  r.w = qlo ? x3 : y3;
  return r;
}

// ---------------- prep: gather/transpose/convert weights into g_img ----------------
// A-fragment layout per 1KB block (mi,ki): lane L holds 16B = 8 f16 =
// W^T[16*mi + (L&15)][32*ki + 8*(L>>4) + 0..7]
__global__ void gnn_prep(const float* __restrict__ W1,  const float* __restrict__ b1,
                         const float* __restrict__ We1, const float* __restrict__ be1,
                         const float* __restrict__ We2, const float* __restrict__ be2,
                         const float* __restrict__ Wd1, const float* __restrict__ bd1,
                         const float* __restrict__ Wd2, const float* __restrict__ bd2,
                         const float* __restrict__ Wo)
{
  int t = blockIdx.x * 256 + threadIdx.x;
  int off = t * 4;
  if (off >= IMG_BYTES) return;
  unsigned val;
  if (off < OFF_W2) {
    int rel = off;
    int mi = rel >> 9, li = (rel >> 4) & 31, j2 = (rel >> 2) & 3;
    int fout = mi * 16 + (li & 15);
    int k0 = (li >> 4) * 8 + j2 * 2;
    val = pack_f16_rne(W1[k0 * 256 + fout], W1[(k0 + 1) * 256 + fout]);
  } else if (off < OFF_W3) {
    int rel = off - OFF_W2;
    int blk = rel >> 10, li = (rel >> 4) & 63, j2 = (rel >> 2) & 3;
    int mi = blk >> 3, ki = blk & 7;
    int fout = mi * 16 + (li & 15);
    int k0 = ki * 32 + (li >> 4) * 8 + j2 * 2;
    val = pack_f16_rne(We1[k0 * 128 + fout], We1[(k0 + 1) * 128 + fout]);
  } else if (off < OFF_W4) {
    int rel = off - OFF_W3;
    int ki = rel >> 10, li = (rel >> 4) & 63, j2 = (rel >> 2) & 3;
    int fo = li & 15;
    int k0 = ki * 32 + (li >> 4) * 8 + j2 * 2;
    float a = (fo < 6) ? We2[k0 * 6 + fo] : 0.0f;
    float b = (fo < 6) ? We2[(k0 + 1) * 6 + fo] : 0.0f;
    val = pack_f16_rne(a, b);
  } else if (off < OFF_W5) {
    int rel = off - OFF_W4;
    int mi = rel >> 10, li = (rel >> 4) & 63, j2 = (rel >> 2) & 3;
    int fout = mi * 16 + (li & 15);
    int k0 = (li >> 4) * 8 + j2 * 2;
    float a = (k0 < 6)     ? Wd1[k0 * 128 + fout]       : 0.0f;
    float b = (k0 + 1 < 6) ? Wd1[(k0 + 1) * 128 + fout] : 0.0f;
    val = pack_f16_rne(a, b);
  } else if (off < OFF_WO) {
    int rel = off - OFF_W5;
    int blk = rel >> 10, li = (rel >> 4) & 63, j2 = (rel >> 2) & 3;
    int mi = blk >> 2, ki = blk & 3;
    int fout = mi * 16 + (li & 15);
    int k0 = ki * 32 + (li >> 4) * 8 + j2 * 2;
    val = pack_f16_rne(Wd2[k0 * 256 + fout], Wd2[(k0 + 1) * 256 + fout]);
  } else if (off < OFF_B1) {
    val = __builtin_bit_cast(unsigned, Wo[(off - OFF_WO) >> 2]);
  } else if (off < OFF_B2) {
    val = __builtin_bit_cast(unsigned, b1[(off - OFF_B1) >> 2]);
  } else if (off < OFF_B3) {
    val = __builtin_bit_cast(unsigned, be1[(off - OFF_B2) >> 2]);
  } else if (off < OFF_B4) {
    int i = (off - OFF_B3) >> 2;
    float v = (i < 6) ? be2[i] : 0.0f;
    val = __builtin_bit_cast(unsigned, v);
  } else if (off < OFF_B5) {
    val = __builtin_bit_cast(unsigned, bd1[(off - OFF_B4) >> 2]);
  } else {
    val = __builtin_bit_cast(unsigned, bd2[(off - OFF_B5) >> 2]);
  }
  *(unsigned*)(g_img + off) = val;
}

static __device__ __forceinline__ void stage_chunk(const char* src, char* dst) {
  __builtin_amdgcn_global_load_lds(
      (const __attribute__((address_space(1))) void*)src,
      (__attribute__((address_space(3))) void*)dst, 16, 0, 0);
}

// ================= K1: L1 -> L2 -> L3, z to d_ws =================
#define L1_PAIR(KO, OUT_G0, OUT_G1) do {                                   \
    half8 Ae = lda(smem, OFF_W1 + (2*(KO))*512 + (ln & 31)*16);            \
    half8 Ao = lda(smem, OFF_W1 + (2*(KO)+1)*512 + (ln & 31)*16);          \
    if (!qlo) { Ae = h8z; Ao = h8z; }                                      \
    f32x4 be_ = ldf4(smem, K1_B1 + (2*(KO))*64 + q*16);                    \
    f32x4 bo_ = ldf4(smem, K1_B1 + (2*(KO)+1)*64 + q*16);                  \
    f32x4 ae0 = mfma16(Ae, b1g0, be_);                                     \
    f32x4 ae1 = mfma16(Ae, b1g1, be_);                                     \
    f32x4 ao0 = mfma16(Ao, b1g0, bo_);                                     \
    f32x4 ao1 = mfma16(Ao, b1g1, bo_);                                     \
    PK2 pe0 = tp(ae0), po0 = tp(ao0), pe1 = tp(ae1), po1 = tp(ao1);        \
    OUT_G0 = xform(pe0, po0, s1, s2, qlo);                                 \
    OUT_G1 = xform(pe1, po1, s1, s2, qlo);                                 \
    FENCE();                                                               \
  } while (0)

#define L2_MI(MI, ACC0, ACC1) do {                                                            \
    f32x4 bb = ldf4(smem, K1_B2 + (MI)*64 + q*16);                                            \
    ACC0 = bb; ACC1 = bb;                                                                     \
    half8 A;                                                                                  \
    A = lda(smem, OFF_W2 + ((MI)*8+0)*1024 + ln*16); ACC0 = mfma16(A, c2g0_0, ACC0); ACC1 = mfma16(A, c2g1_0, ACC1); \
    A = lda(smem, OFF_W2 + ((MI)*8+1)*1024 + ln*16); ACC0 = mfma16(A, c2g0_1, ACC0); ACC1 = mfma16(A, c2g1_1, ACC1); \
    A = lda(smem, OFF_W2 + ((MI)*8+2)*1024 + ln*16); ACC0 = mfma16(A, c2g0_2, ACC0); ACC1 = mfma16(A, c2g1_2, ACC1); \
    A = lda(smem, OFF_W2 + ((MI)*8+3)*1024 + ln*16); ACC0 = mfma16(A, c2g0_3, ACC0); ACC1 = mfma16(A, c2g1_3, ACC1); \
    A = lda(smem, OFF_W2 + ((MI)*8+4)*1024 + ln*16); ACC0 = mfma16(A, c2g0_4, ACC0); ACC1 = mfma16(A, c2g1_4, ACC1); \
    A = lda(smem, OFF_W2 + ((MI)*8+5)*1024 + ln*16); ACC0 = mfma16(A, c2g0_5, ACC0); ACC1 = mfma16(A, c2g1_5, ACC1); \
    A = lda(smem, OFF_W2 + ((MI)*8+6)*1024 + ln*16); ACC0 = mfma16(A, c2g0_6, ACC0); ACC1 = mfma16(A, c2g1_6, ACC1); \
    A = lda(smem, OFF_W2 + ((MI)*8+7)*1024 + ln*16); ACC0 = mfma16(A, c2g0_7, ACC0); ACC1 = mfma16(A, c2g1_7, ACC1); \
  } while (0)

#define L2_PAIR(KO, OUT_G0, OUT_G1) do {                                   \
    f32x4 ve0, ve1, vo0, vo1;                                              \
    L2_MI(2*(KO),   ve0, ve1);                                             \
    FENCE();                                                               \
    L2_MI(2*(KO)+1, vo0, vo1);                                             \
    PK2 pe0 = tp(ve0), po0 = tp(vo0), pe1 = tp(ve1), po1 = tp(vo1);        \
    OUT_G0 = xform(pe0, po0, s1, s2, qlo);                                 \
    OUT_G1 = xform(pe1, po1, s1, s2, qlo);                                 \
    FENCE();                                                               \
  } while (0)

__global__ __launch_bounds__(512)
void gnn_k1(const float* __restrict__ ea, int4v* __restrict__ zbuf)
{
  __shared__ __align__(16) char smem[K1_LDS];
  const int tid = threadIdx.x;
  const int wv = tid >> 6, ln = tid & 63;

  // stage [0,77824) weights + [OFF_B1, +2048) biases -> LDS, contiguous dst
#pragma unroll 1
  for (int r = 0; r < 10; ++r) {
    int cb = (r * 8 + wv) << 6;               // wave-uniform chunk base
    if (cb < 4992) {
      int src = (cb < 4864) ? cb * 16 : OFF_B1 + (cb - 4864) * 16;
      stage_chunk(g_img + src + ln * 16, smem + (size_t)cb * 16 + ln * 16);
    }
  }
  __syncthreads();

  const int q = ln >> 4, c = ln & 15;
  const bool qlo = (q < 2);
  const int s1 = ((q & 1) << 5) + c;
  const int s2 = s1 + 16;
  const int4v zi4 = {0, 0, 0, 0};
  const half8 h8z = __builtin_bit_cast(half8, zi4);

  const int NT = (N_NODES + 255) / 256;
#pragma unroll 1
  for (int t = blockIdx.x; t < NT; t += gridDim.x) {
    const int base = t * 256 + wv * 32;

    // ---- L1 input: edge_attr as X^T, f16 B-frags ----
    int nl = base + (q >> 1) * 16 + c;
    if (nl > N_NODES - 1) nl = N_NODES - 1;
    const f32x4* ea4 = (const f32x4*)ea;
    size_t eb = (size_t)nl * 4 + (size_t)((q & 1) * 2);
    f32x4 vlo = ea4[eb];
    f32x4 vhi = ea4[eb + 1];
    int p0 = pkrtz(vlo.x, vlo.y), p1 = pkrtz(vlo.z, vlo.w);
    int p2 = pkrtz(vhi.x, vhi.y), p3 = pkrtz(vhi.z, vhi.w);
    int4v b1g0, b1g1;
    b1g0.x = qlo ? p0 : 0; b1g0.y = qlo ? p1 : 0;
    b1g0.z = qlo ? p2 : 0; b1g0.w = qlo ? p3 : 0;
    int sh = (ln + 32) & 63;
    int r0 = __shfl(p0, sh, 64), r1 = __shfl(p1, sh, 64);
    int r2 = __shfl(p2, sh, 64), r3 = __shfl(p3, sh, 64);
    b1g1.x = qlo ? r0 : 0; b1g1.y = qlo ? r1 : 0;
    b1g1.z = qlo ? r2 : 0; b1g1.w = qlo ? r3 : 0;

    // ---- L1: 16 -> 256 -> L2 B-frags ----
    int4v c2g0_0, c2g0_1, c2g0_2, c2g0_3, c2g0_4, c2g0_5, c2g0_6, c2g0_7;
    int4v c2g1_0, c2g1_1, c2g1_2, c2g1_3, c2g1_4, c2g1_5, c2g1_6, c2g1_7;
    L1_PAIR(0, c2g0_0, c2g1_0);
    L1_PAIR(1, c2g0_1, c2g1_1);
    L1_PAIR(2, c2g0_2, c2g1_2);
    L1_PAIR(3, c2g0_3, c2g1_3);
    L1_PAIR(4, c2g0_4, c2g1_4);
    L1_PAIR(5, c2g0_5, c2g1_5);
    L1_PAIR(6, c2g0_6, c2g1_6);
    L1_PAIR(7, c2g0_7, c2g1_7);

    // ---- L2: 256 -> 128 -> L3 B-frags ----
    int4v c3g0_0, c3g0_1, c3g0_2, c3g0_3;
    int4v c3g1_0, c3g1_1, c3g1_2, c3g1_3;
    L2_PAIR(0, c3g0_0, c3g1_0);
    L2_PAIR(1, c3g0_1, c3g1_1);
    L2_PAIR(2, c3g0_2, c3g1_2);
    L2_PAIR(3, c3g0_3, c3g1_3);

    // ---- L3: 128 -> 6 ----
    f32x4 bb3 = ldf4(smem, K1_B3 + q * 16);
    f32x4 z0 = bb3, z1 = bb3;
    half8 A;
    A = lda(smem, OFF_W3 + 0 * 1024 + ln * 16); z0 = mfma16(A, c3g0_0, z0); z1 = mfma16(A, c3g1_0, z1);
    A = lda(smem, OFF_W3 + 1 * 1024 + ln * 16); z0 = mfma16(A, c3g0_1, z0); z1 = mfma16(A, c3g1_1, z1);
    A = lda(smem, OFF_W3 + 2 * 1024 + ln * 16); z0 = mfma16(A, c3g0_2, z0); z1 = mfma16(A, c3g1_2, z1);
    A = lda(smem, OFF_W3 + 3 * 1024 + ln * 16); z0 = mfma16(A, c3g0_3, z0); z1 = mfma16(A, c3g1_3, z1);
    PK2 p3g0 = tp(z0);
    PK2 p3g1 = tp(z1);

    // ---- store z (rows 0..7 live on lanes 0..31; rows 8..15 are zeros) ----
    if (ln < 32) {
      int4v zv;
      zv.x = p3g0.lo; zv.y = p3g0.hi; zv.z = p3g1.lo; zv.w = p3g1.hi;
      zbuf[(size_t)(t * 8 + wv) * 32 + ln] = zv;
    }
  }
}

// ================= K2: L4 -> L5 -> out =================
#define L4_MI(MI, ACC0, ACC1) do {                                         \
    f32x4 bb = ldf4(smem, K2_B4 + (MI)*64 + q*16);                         \
    half8 A = lda(smem, K2_W4 + (MI)*1024 + ln*16);                        \
    ACC0 = mfma16(A, b4g0, bb);                                            \
    ACC1 = mfma16(A, b4g1, bb);                                            \
  } while (0)

#define L4_PAIR(KO, OUT_G0, OUT_G1) do {                                   \
    f32x4 ve0, ve1, vo0, vo1;                                              \
    L4_MI(2*(KO),   ve0, ve1);                                             \
    L4_MI(2*(KO)+1, vo0, vo1);                                             \
    PK2 pe0 = tp(ve0), po0 = tp(vo0), pe1 = tp(ve1), po1 = tp(vo1);        \
    OUT_G0 = xform(pe0, po0, s1, s2, qlo);                                 \
    OUT_G1 = xform(pe1, po1, s1, s2, qlo);                                 \
    FENCE();                                                               \
  } while (0)

#define L5_MI(MI) do {                                                                        \
    f32x4 bb = ldf4(smem, K2_B5 + (MI)*64 + q*16);                                            \
    f32x4 a0 = bb, a1 = bb;                                                                   \
    half8 A;                                                                                  \
    A = lda(smem, K2_W5 + ((MI)*4+0)*1024 + ln*16); a0 = mfma16(A, c5g0_0, a0); a1 = mfma16(A, c5g1_0, a1); \
    A = lda(smem, K2_W5 + ((MI)*4+1)*1024 + ln*16); a0 = mfma16(A, c5g0_1, a0); a1 = mfma16(A, c5g1_1, a1); \
    A = lda(smem, K2_W5 + ((MI)*4+2)*1024 + ln*16); a0 = mfma16(A, c5g0_2, a0); a1 = mfma16(A, c5g1_2, a1); \
    A = lda(smem, K2_W5 + ((MI)*4+3)*1024 + ln*16); a0 = mfma16(A, c5g0_3, a0); a1 = mfma16(A, c5g1_3, a1); \
    f32x4 wo = ldf4(smem, K2_WO + (MI)*64 + q*16);                                            \
    part0 += tanh_f(a0.x)*wo.x + tanh_f(a0.y)*wo.y + tanh_f(a0.z)*wo.z + tanh_f(a0.w)*wo.w;   \
    part1 += tanh_f(a1.x)*wo.x + tanh_f(a1.y)*wo.y + tanh_f(a1.z)*wo.z + tanh_f(a1.w)*wo.w;   \
    FENCE();                                                                                  \
  } while (0)

__global__ __launch_bounds__(512)
void gnn_k2(const int4v* __restrict__ zbuf, float* __restrict__ out,
            const float* __restrict__ bo_p)
{
  __shared__ __align__(16) char smem[K2_LDS];
  const int tid = threadIdx.x;
  const int wv = tid >> 6, ln = tid & 63;

  // stage W4 | W5+WO | B4+B5 -> LDS contiguous
#pragma unroll 1
  for (int r = 0; r < 10; ++r) {
    int cb = (r * 8 + wv) << 6;
    if (cb < 4800) {
      int src;
      if (cb < 512)       src = OFF_W4 + cb * 16;
      else if (cb < 4672) src = OFF_W5 + (cb - 512) * 16;
      else                src = OFF_B4 + (cb - 4672) * 16;
      stage_chunk(g_img + src + ln * 16, smem + (size_t)cb * 16 + ln * 16);
    }
  }
  __syncthreads();

  const int q = ln >> 4, c = ln & 15;
  const bool qlo = (q < 2);
  const int s1 = ((q & 1) << 5) + c;
  const int s2 = s1 + 16;
  const float bo = *bo_p;

  const int NT = (N_NODES + 255) / 256;
#pragma unroll 1
  for (int t = blockIdx.x; t < NT; t += gridDim.x) {
    const int base = t * 256 + wv * 32;

    // ---- reload z (valid on lanes 0..31; shuffle sources for qlo are <32) ----
    int4v zv = {0, 0, 0, 0};
    if (ln < 32) zv = zbuf[(size_t)(t * 8 + wv) * 32 + ln];
    PK2 p3g0, p3g1;
    p3g0.lo = zv.x; p3g0.hi = zv.y; p3g1.lo = zv.z; p3g1.hi = zv.w;

    // ---- L4 input: 6 feats (K padded to 32; k>=16 lanes zeroed) ----
    int4v b4g0, b4g1;
    {
      int a0 = __shfl(p3g0.lo, s1, 64), a1 = __shfl(p3g0.hi, s1, 64);
      int a2 = __shfl(p3g0.lo, s2, 64), a3 = __shfl(p3g0.hi, s2, 64);
      b4g0.x = qlo ? a0 : 0; b4g0.y = qlo ? a1 : 0;
      b4g0.z = qlo ? a2 : 0; b4g0.w = qlo ? a3 : 0;
      int d0 = __shfl(p3g1.lo, s1, 64), d1 = __shfl(p3g1.hi, s1, 64);
      int d2 = __shfl(p3g1.lo, s2, 64), d3 = __shfl(p3g1.hi, s2, 64);
      b4g1.x = qlo ? d0 : 0; b4g1.y = qlo ? d1 : 0;
      b4g1.z = qlo ? d2 : 0; b4g1.w = qlo ? d3 : 0;
    }

    // ---- L4: 6 -> 128 -> L5 B-frags ----
    int4v c5g0_0, c5g0_1, c5g0_2, c5g0_3;
    int4v c5g1_0, c5g1_1, c5g1_2, c5g1_3;
    L4_PAIR(0, c5g0_0, c5g1_0);
    L4_PAIR(1, c5g0_1, c5g1_1);
    L4_PAIR(2, c5g0_2, c5g1_2);
    L4_PAIR(3, c5g0_3, c5g1_3);

    // ---- L5: 128 -> 256 fused with L6: out = sigmoid(tanh(d).Wo + bo) ----
    float part0 = 0.0f, part1 = 0.0f;
    L5_MI(0);  L5_MI(1);  L5_MI(2);  L5_MI(3);
    L5_MI(4);  L5_MI(5);  L5_MI(6);  L5_MI(7);
    L5_MI(8);  L5_MI(9);  L5_MI(10); L5_MI(11);
    L5_MI(12); L5_MI(13); L5_MI(14); L5_MI(15);

    part0 += __shfl_xor(part0, 16, 64); part0 += __shfl_xor(part0, 32, 64);
    part1 += __shfl_xor(part1, 16, 64); part1 += __shfl_xor(part1, 32, 64);
    if (q < 2) {
      int node = base + q * 16 + c;
      if (node < N_NODES) {
        float v = ((q == 0) ? part0 : part1) + bo;
        out[node] = sigmoid_f(v);
      }
    }
  }
}

extern "C" void kernel_launch(void* const* d_in, const int* in_sizes, int n_in,
                              void* d_out, int out_size, void* d_ws, size_t ws_size,
                              hipStream_t stream) {
  (void)in_sizes; (void)n_in; (void)ws_size; (void)out_size;
  const float* ea  = (const float*)d_in[2];
  const float* W1  = (const float*)d_in[3];
  const float* b1  = (const float*)d_in[4];
  const float* We1 = (const float*)d_in[5];
  const float* be1 = (const float*)d_in[6];
  const float* We2 = (const float*)d_in[7];
  const float* be2 = (const float*)d_in[8];
  const float* Wd1 = (const float*)d_in[9];
  const float* bd1 = (const float*)d_in[10];
  const float* Wd2 = (const float*)d_in[11];
  const float* bd2 = (const float*)d_in[12];
  const float* Wo  = (const float*)d_in[13];
  const float* bo  = (const float*)d_in[14];

  gnn_prep<<<dim3((IMG_BYTES / 4 + 255) / 256), dim3(256), 0, stream>>>(
      W1, b1, We1, be1, We2, be2, Wd1, bd1, Wd2, bd2, Wo);
  gnn_k1<<<dim3(512), dim3(512), 0, stream>>>(ea, (int4v*)d_ws);
  gnn_k2<<<dim3(512), dim3(512), 0, stream>>>((const int4v*)d_ws, (float*)d_out, bo);
}

// Round 6
// 249.265 us; speedup vs baseline: 3.9531x; 1.0512x over previous
//
#include <hip/hip_runtime.h>

// Per-node MLP 16->256->128->6->128->256->1 (tanh...sigmoid) on
// edge_attr.reshape(500000,16). x / edge_index are dead inputs.
//
// R6: R5's split-kernel structure (no spills) kept. New: the C->B layout
// shuffles (~264 ds_bpermute/wave-tile, the LDS-pipe + conflict load) are
// ELIMINATED by baking a k-permutation into the A-weight fragments
// (kval = 32ki + 4q + 16*(j>>2) + (j&3)), so each lane's own C-fragment
// registers [pe.lo, pe.hi, po.lo, po.hi] are directly the next layer's
// B-operand. k2's z-reload likewise feeds [z.lo, z.hi, 0, 0] with no
// cross-lane ops.

#define N_NODES 500000

// ---- weight-image layout in g_img (bytes) ----
#define OFF_W1 0        // 16 x 512B  (L1: K=16, standard k-order)
#define OFF_W2 8192     // 64 x 1KB   (L2: 256->128, mi*8+ki, permuted k)
#define OFF_W3 73728    // 4  x 1KB   (L3: 128->16(6 valid), ki, permuted k)
#define OFF_W4 77824    // 8  x 1KB   (L4: z C-layout feed, K pad 32)
#define OFF_W5 86016    // 64 x 1KB   (L5: 128->256, mi*4+ki, permuted k)
#define OFF_WO 151552   // 256 f32
#define OFF_B1 152576   // 256 f32
#define OFF_B2 153600   // 128 f32
#define OFF_B3 154112   // 16 f32 (6 valid)
#define OFF_B4 154176   // 128 f32
#define OFF_B5 154688   // 256 f32
#define IMG_BYTES 155712
#define IMG_ALLOC 156672   // padded: K2 staging tail reads past IMG_BYTES

// ---- K1 LDS: [W1 W2 W3][B1 B2 B3] ----
#define K1_LDS   79872
#define K1_B1    77824
#define K1_B2    78848
#define K1_B3    79360
// ---- K2 LDS: [W4][W5 WO][B4 B5] ----
#define K2_LDS   76800
#define K2_W4    0
#define K2_W5    8192
#define K2_WO    73728
#define K2_B4    74752
#define K2_B5    75264

typedef _Float16 half8  __attribute__((ext_vector_type(8)));
typedef __fp16   pk16x2 __attribute__((ext_vector_type(2)));
typedef float    f32x4  __attribute__((ext_vector_type(4)));
typedef int      int4v  __attribute__((ext_vector_type(4)));

__device__ __align__(16) char g_img[IMG_ALLOC];

static __device__ __forceinline__ unsigned pack_f16_rne(float a, float b) {
  _Float16 ha = (_Float16)a, hb = (_Float16)b;
  unsigned short ua = __builtin_bit_cast(unsigned short, ha);
  unsigned short ub = __builtin_bit_cast(unsigned short, hb);
  return (unsigned)ua | ((unsigned)ub << 16);
}
static __device__ __forceinline__ int pkrtz(float a, float b) {
  pk16x2 h = __builtin_amdgcn_cvt_pkrtz(a, b);
  return __builtin_bit_cast(int, h);
}
static __device__ __forceinline__ float tanh_f(float x) {
  float e = __builtin_amdgcn_exp2f(x * 2.8853900817779268f);
  float r = __builtin_amdgcn_rcpf(e + 1.0f);
  return __builtin_fmaf(-2.0f, r, 1.0f);
}
static __device__ __forceinline__ float sigmoid_f(float x) {
  float e = __builtin_amdgcn_exp2f(x * -1.4426950408889634f);
  return __builtin_amdgcn_rcpf(1.0f + e);
}
static __device__ __forceinline__ f32x4 mfma16(half8 a, int4v b, f32x4 c) {
  return __builtin_amdgcn_mfma_f32_16x16x32_f16(a, __builtin_bit_cast(half8, b), c, 0, 0, 0);
}
static __device__ __forceinline__ half8 lda(const char* smem, int off) {
  return *(const half8*)(smem + off);
}
static __device__ __forceinline__ f32x4 ldf4(const char* smem, int off) {
  return *(const f32x4*)(smem + off);
}
#define FENCE() __builtin_amdgcn_sched_barrier(0)

struct PK2 { int lo, hi; };
static __device__ __forceinline__ PK2 tp(f32x4 a) {
  PK2 p;
  p.lo = pkrtz(tanh_f(a.x), tanh_f(a.y));   // rows 4q+0, 4q+1
  p.hi = pkrtz(tanh_f(a.z), tanh_f(a.w));   // rows 4q+2, 4q+3
  return p;
}

// ---------------- prep: gather/transpose/convert weights into g_img ----------------
// Standard A-layout (W1): lane L, pair j2 holds k0 = (L>>4)*8 + 2*j2.
// PERMUTED A-layout (W2/W3/W5, consuming C-layout activations):
//   k0 = ki*32 + 4*(L>>4) + 16*(j2>>1) + 2*(j2&1)
// so that B-frag = [pe.lo, pe.hi, po.lo, po.hi] of the SAME lane is correct.
// W4 (consuming z C-layout, K padded to 32): j2=0 -> k0=4q, j2=1 -> k0=4q+2,
// j2>=2 -> zero (B regs 2,3 are zero).
__global__ void gnn_prep(const float* __restrict__ W1,  const float* __restrict__ b1,
                         const float* __restrict__ We1, const float* __restrict__ be1,
                         const float* __restrict__ We2, const float* __restrict__ be2,
                         const float* __restrict__ Wd1, const float* __restrict__ bd1,
                         const float* __restrict__ Wd2, const float* __restrict__ bd2,
                         const float* __restrict__ Wo)
{
  int t = blockIdx.x * 256 + threadIdx.x;
  int off = t * 4;
  if (off >= IMG_BYTES) return;
  unsigned val;
  if (off < OFF_W2) {                     // L1 (K=16): standard order
    int rel = off;
    int mi = rel >> 9, li = (rel >> 4) & 31, j2 = (rel >> 2) & 3;
    int fout = mi * 16 + (li & 15);
    int k0 = (li >> 4) * 8 + j2 * 2;
    val = pack_f16_rne(W1[k0 * 256 + fout], W1[(k0 + 1) * 256 + fout]);
  } else if (off < OFF_W3) {              // L2: 256->128, permuted k
    int rel = off - OFF_W2;
    int blk = rel >> 10, li = (rel >> 4) & 63, j2 = (rel >> 2) & 3;
    int mi = blk >> 3, ki = blk & 7;
    int fout = mi * 16 + (li & 15);
    int k0 = ki * 32 + 4 * (li >> 4) + 16 * (j2 >> 1) + 2 * (j2 & 1);
    val = pack_f16_rne(We1[k0 * 128 + fout], We1[(k0 + 1) * 128 + fout]);
  } else if (off < OFF_W4) {              // L3: 128->6 (fout pad 16), permuted k
    int rel = off - OFF_W3;
    int ki = rel >> 10, li = (rel >> 4) & 63, j2 = (rel >> 2) & 3;
    int fo = li & 15;
    int k0 = ki * 32 + 4 * (li >> 4) + 16 * (j2 >> 1) + 2 * (j2 & 1);
    float a = (fo < 6) ? We2[k0 * 6 + fo] : 0.0f;
    float b = (fo < 6) ? We2[(k0 + 1) * 6 + fo] : 0.0f;
    val = pack_f16_rne(a, b);
  } else if (off < OFF_W5) {              // L4: z C-layout feed
    int rel = off - OFF_W4;
    int mi = rel >> 10, li = (rel >> 4) & 63, j2 = (rel >> 2) & 3;
    int fout = mi * 16 + (li & 15);
    int qa = li >> 4;
    unsigned v = 0;
    if (j2 < 2) {
      int k0 = 4 * qa + 2 * j2;
      float a = (k0 < 6)     ? Wd1[k0 * 128 + fout]       : 0.0f;
      float b = (k0 + 1 < 6) ? Wd1[(k0 + 1) * 128 + fout] : 0.0f;
      v = pack_f16_rne(a, b);
    }
    val = v;
  } else if (off < OFF_WO) {              // L5: 128->256, permuted k
    int rel = off - OFF_W5;
    int blk = rel >> 10, li = (rel >> 4) & 63, j2 = (rel >> 2) & 3;
    int mi = blk >> 2, ki = blk & 3;
    int fout = mi * 16 + (li & 15);
    int k0 = ki * 32 + 4 * (li >> 4) + 16 * (j2 >> 1) + 2 * (j2 & 1);
    val = pack_f16_rne(Wd2[k0 * 256 + fout], Wd2[(k0 + 1) * 256 + fout]);
  } else if (off < OFF_B1) {
    val = __builtin_bit_cast(unsigned, Wo[(off - OFF_WO) >> 2]);
  } else if (off < OFF_B2) {
    val = __builtin_bit_cast(unsigned, b1[(off - OFF_B1) >> 2]);
  } else if (off < OFF_B3) {
    val = __builtin_bit_cast(unsigned, be1[(off - OFF_B2) >> 2]);
  } else if (off < OFF_B4) {
    int i = (off - OFF_B3) >> 2;
    float v = (i < 6) ? be2[i] : 0.0f;
    val = __builtin_bit_cast(unsigned, v);
  } else if (off < OFF_B5) {
    val = __builtin_bit_cast(unsigned, bd1[(off - OFF_B4) >> 2]);
  } else {
    val = __builtin_bit_cast(unsigned, bd2[(off - OFF_B5) >> 2]);
  }
  *(unsigned*)(g_img + off) = val;
}

static __device__ __forceinline__ void stage_chunk(const char* src, char* dst) {
  __builtin_amdgcn_global_load_lds(
      (const __attribute__((address_space(1))) void*)src,
      (__attribute__((address_space(3))) void*)dst, 16, 0, 0);
}

// ================= K1: L1 -> L2 -> L3, z to d_ws =================
#define L1_PAIR(KO, OUT_G0, OUT_G1) do {                                   \
    half8 Ae = lda(smem, OFF_W1 + (2*(KO))*512 + (ln & 31)*16);            \
    half8 Ao = lda(smem, OFF_W1 + (2*(KO)+1)*512 + (ln & 31)*16);          \
    if (!qlo) { Ae = h8z; Ao = h8z; }                                      \
    f32x4 be_ = ldf4(smem, K1_B1 + (2*(KO))*64 + q*16);                    \
    f32x4 bo_ = ldf4(smem, K1_B1 + (2*(KO)+1)*64 + q*16);                  \
    f32x4 ae0 = mfma16(Ae, b1g0, be_);                                     \
    f32x4 ae1 = mfma16(Ae, b1g1, be_);                                     \
    f32x4 ao0 = mfma16(Ao, b1g0, bo_);                                     \
    f32x4 ao1 = mfma16(Ao, b1g1, bo_);                                     \
    PK2 pe0 = tp(ae0), po0 = tp(ao0), pe1 = tp(ae1), po1 = tp(ao1);        \
    OUT_G0.x = pe0.lo; OUT_G0.y = pe0.hi; OUT_G0.z = po0.lo; OUT_G0.w = po0.hi; \
    OUT_G1.x = pe1.lo; OUT_G1.y = pe1.hi; OUT_G1.z = po1.lo; OUT_G1.w = po1.hi; \
    FENCE();                                                               \
  } while (0)

#define L2_MI(MI, ACC0, ACC1) do {                                                            \
    f32x4 bb = ldf4(smem, K1_B2 + (MI)*64 + q*16);                                            \
    ACC0 = bb; ACC1 = bb;                                                                     \
    half8 A;                                                                                  \
    A = lda(smem, OFF_W2 + ((MI)*8+0)*1024 + ln*16); ACC0 = mfma16(A, c2g0_0, ACC0); ACC1 = mfma16(A, c2g1_0, ACC1); \
    A = lda(smem, OFF_W2 + ((MI)*8+1)*1024 + ln*16); ACC0 = mfma16(A, c2g0_1, ACC0); ACC1 = mfma16(A, c2g1_1, ACC1); \
    A = lda(smem, OFF_W2 + ((MI)*8+2)*1024 + ln*16); ACC0 = mfma16(A, c2g0_2, ACC0); ACC1 = mfma16(A, c2g1_2, ACC1); \
    A = lda(smem, OFF_W2 + ((MI)*8+3)*1024 + ln*16); ACC0 = mfma16(A, c2g0_3, ACC0); ACC1 = mfma16(A, c2g1_3, ACC1); \
    A = lda(smem, OFF_W2 + ((MI)*8+4)*1024 + ln*16); ACC0 = mfma16(A, c2g0_4, ACC0); ACC1 = mfma16(A, c2g1_4, ACC1); \
    A = lda(smem, OFF_W2 + ((MI)*8+5)*1024 + ln*16); ACC0 = mfma16(A, c2g0_5, ACC0); ACC1 = mfma16(A, c2g1_5, ACC1); \
    A = lda(smem, OFF_W2 + ((MI)*8+6)*1024 + ln*16); ACC0 = mfma16(A, c2g0_6, ACC0); ACC1 = mfma16(A, c2g1_6, ACC1); \
    A = lda(smem, OFF_W2 + ((MI)*8+7)*1024 + ln*16); ACC0 = mfma16(A, c2g0_7, ACC0); ACC1 = mfma16(A, c2g1_7, ACC1); \
  } while (0)

#define L2_PAIR(KO, OUT_G0, OUT_G1) do {                                   \
    f32x4 ve0, ve1, vo0, vo1;                                              \
    L2_MI(2*(KO),   ve0, ve1);                                             \
    FENCE();                                                               \
    L2_MI(2*(KO)+1, vo0, vo1);                                             \
    PK2 pe0 = tp(ve0), po0 = tp(vo0), pe1 = tp(ve1), po1 = tp(vo1);        \
    OUT_G0.x = pe0.lo; OUT_G0.y = pe0.hi; OUT_G0.z = po0.lo; OUT_G0.w = po0.hi; \
    OUT_G1.x = pe1.lo; OUT_G1.y = pe1.hi; OUT_G1.z = po1.lo; OUT_G1.w = po1.hi; \
    FENCE();                                                               \
  } while (0)

__global__ __launch_bounds__(512)
void gnn_k1(const float* __restrict__ ea, int4v* __restrict__ zbuf)
{
  __shared__ __align__(16) char smem[K1_LDS];
  const int tid = threadIdx.x;
  const int wv = tid >> 6, ln = tid & 63;

#pragma unroll 1
  for (int r = 0; r < 10; ++r) {
    int cb = (r * 8 + wv) << 6;
    if (cb < 4992) {
      int src = (cb < 4864) ? cb * 16 : OFF_B1 + (cb - 4864) * 16;
      stage_chunk(g_img + src + ln * 16, smem + (size_t)cb * 16 + ln * 16);
    }
  }
  __syncthreads();

  const int q = ln >> 4, c = ln & 15;
  const bool qlo = (q < 2);
  const int4v zi4 = {0, 0, 0, 0};
  const half8 h8z = __builtin_bit_cast(half8, zi4);

  const int NT = (N_NODES + 255) / 256;
#pragma unroll 1
  for (int t = blockIdx.x; t < NT; t += gridDim.x) {
    const int base = t * 256 + wv * 32;

    // ---- L1 input: edge_attr as X^T, standard B-frags ----
    int nl = base + (q >> 1) * 16 + c;
    if (nl > N_NODES - 1) nl = N_NODES - 1;
    const f32x4* ea4 = (const f32x4*)ea;
    size_t eb = (size_t)nl * 4 + (size_t)((q & 1) * 2);
    f32x4 vlo = ea4[eb];
    f32x4 vhi = ea4[eb + 1];
    int p0 = pkrtz(vlo.x, vlo.y), p1 = pkrtz(vlo.z, vlo.w);
    int p2 = pkrtz(vhi.x, vhi.y), p3 = pkrtz(vhi.z, vhi.w);
    int4v b1g0, b1g1;
    b1g0.x = qlo ? p0 : 0; b1g0.y = qlo ? p1 : 0;
    b1g0.z = qlo ? p2 : 0; b1g0.w = qlo ? p3 : 0;
    int sh = (ln + 32) & 63;
    int r0 = __shfl(p0, sh, 64), r1 = __shfl(p1, sh, 64);
    int r2 = __shfl(p2, sh, 64), r3 = __shfl(p3, sh, 64);
    b1g1.x = qlo ? r0 : 0; b1g1.y = qlo ? r1 : 0;
    b1g1.z = qlo ? r2 : 0; b1g1.w = qlo ? r3 : 0;

    // ---- L1: 16 -> 256 -> L2 B-frags (in-lane, permuted-k A) ----
    int4v c2g0_0, c2g0_1, c2g0_2, c2g0_3, c2g0_4, c2g0_5, c2g0_6, c2g0_7;
    int4v c2g1_0, c2g1_1, c2g1_2, c2g1_3, c2g1_4, c2g1_5, c2g1_6, c2g1_7;
    L1_PAIR(0, c2g0_0, c2g1_0);
    L1_PAIR(1, c2g0_1, c2g1_1);
    L1_PAIR(2, c2g0_2, c2g1_2);
    L1_PAIR(3, c2g0_3, c2g1_3);
    L1_PAIR(4, c2g0_4, c2g1_4);
    L1_PAIR(5, c2g0_5, c2g1_5);
    L1_PAIR(6, c2g0_6, c2g1_6);
    L1_PAIR(7, c2g0_7, c2g1_7);

    // ---- L2: 256 -> 128 -> L3 B-frags ----
    int4v c3g0_0, c3g0_1, c3g0_2, c3g0_3;
    int4v c3g1_0, c3g1_1, c3g1_2, c3g1_3;
    L2_PAIR(0, c3g0_0, c3g1_0);
    L2_PAIR(1, c3g0_1, c3g1_1);
    L2_PAIR(2, c3g0_2, c3g1_2);
    L2_PAIR(3, c3g0_3, c3g1_3);

    // ---- L3: 128 -> 6 ----
    f32x4 bb3 = ldf4(smem, K1_B3 + q * 16);
    f32x4 z0 = bb3, z1 = bb3;
    half8 A;
    A = lda(smem, OFF_W3 + 0 * 1024 + ln * 16); z0 = mfma16(A, c3g0_0, z0); z1 = mfma16(A, c3g1_0, z1);
    A = lda(smem, OFF_W3 + 1 * 1024 + ln * 16); z0 = mfma16(A, c3g0_1, z0); z1 = mfma16(A, c3g1_1, z1);
    A = lda(smem, OFF_W3 + 2 * 1024 + ln * 16); z0 = mfma16(A, c3g0_2, z0); z1 = mfma16(A, c3g1_2, z1);
    A = lda(smem, OFF_W3 + 3 * 1024 + ln * 16); z0 = mfma16(A, c3g0_3, z0); z1 = mfma16(A, c3g1_3, z1);
    PK2 p3g0 = tp(z0);
    PK2 p3g1 = tp(z1);

    // ---- store z C-layout (rows 0..7 on lanes 0..31; rows 8..15 = 0) ----
    if (ln < 32) {
      int4v zv;
      zv.x = p3g0.lo; zv.y = p3g0.hi; zv.z = p3g1.lo; zv.w = p3g1.hi;
      zbuf[(size_t)(t * 8 + wv) * 32 + ln] = zv;
    }
  }
}

// ================= K2: L4 -> L5 -> out =================
#define L4_MI(MI, ACC0, ACC1) do {                                         \
    f32x4 bb = ldf4(smem, K2_B4 + (MI)*64 + q*16);                         \
    half8 A = lda(smem, K2_W4 + (MI)*1024 + ln*16);                        \
    ACC0 = mfma16(A, b4g0, bb);                                            \
    ACC1 = mfma16(A, b4g1, bb);                                            \
  } while (0)

#define L4_PAIR(KO, OUT_G0, OUT_G1) do {                                   \
    f32x4 ve0, ve1, vo0, vo1;                                              \
    L4_MI(2*(KO),   ve0, ve1);                                             \
    L4_MI(2*(KO)+1, vo0, vo1);                                             \
    PK2 pe0 = tp(ve0), po0 = tp(vo0), pe1 = tp(ve1), po1 = tp(vo1);        \
    OUT_G0.x = pe0.lo; OUT_G0.y = pe0.hi; OUT_G0.z = po0.lo; OUT_G0.w = po0.hi; \
    OUT_G1.x = pe1.lo; OUT_G1.y = pe1.hi; OUT_G1.z = po1.lo; OUT_G1.w = po1.hi; \
    FENCE();                                                               \
  } while (0)

#define L5_MI(MI) do {                                                                        \
    f32x4 bb = ldf4(smem, K2_B5 + (MI)*64 + q*16);                                            \
    f32x4 a0 = bb, a1 = bb;                                                                   \
    half8 A;                                                                                  \
    A = lda(smem, K2_W5 + ((MI)*4+0)*1024 + ln*16); a0 = mfma16(A, c5g0_0, a0); a1 = mfma16(A, c5g1_0, a1); \
    A = lda(smem, K2_W5 + ((MI)*4+1)*1024 + ln*16); a0 = mfma16(A, c5g0_1, a0); a1 = mfma16(A, c5g1_1, a1); \
    A = lda(smem, K2_W5 + ((MI)*4+2)*1024 + ln*16); a0 = mfma16(A, c5g0_2, a0); a1 = mfma16(A, c5g1_2, a1); \
    A = lda(smem, K2_W5 + ((MI)*4+3)*1024 + ln*16); a0 = mfma16(A, c5g0_3, a0); a1 = mfma16(A, c5g1_3, a1); \
    f32x4 wo = ldf4(smem, K2_WO + (MI)*64 + q*16);                                            \
    part0 += tanh_f(a0.x)*wo.x + tanh_f(a0.y)*wo.y + tanh_f(a0.z)*wo.z + tanh_f(a0.w)*wo.w;   \
    part1 += tanh_f(a1.x)*wo.x + tanh_f(a1.y)*wo.y + tanh_f(a1.z)*wo.z + tanh_f(a1.w)*wo.w;   \
    FENCE();                                                                                  \
  } while (0)

__global__ __launch_bounds__(512)
void gnn_k2(const int4v* __restrict__ zbuf, float* __restrict__ out,
            const float* __restrict__ bo_p)
{
  __shared__ __align__(16) char smem[K2_LDS];
  const int tid = threadIdx.x;
  const int wv = tid >> 6, ln = tid & 63;

#pragma unroll 1
  for (int r = 0; r < 10; ++r) {
    int cb = (r * 8 + wv) << 6;
    if (cb < 4800) {
      int src;
      if (cb < 512)       src = OFF_W4 + cb * 16;
      else if (cb < 4672) src = OFF_W5 + (cb - 512) * 16;   // W5+WO contiguous
      else                src = OFF_B4 + (cb - 4672) * 16;
      stage_chunk(g_img + src + ln * 16, smem + (size_t)cb * 16 + ln * 16);
    }
  }
  __syncthreads();

  const int q = ln >> 4, c = ln & 15;
  const float bo = *bo_p;

  const int NT = (N_NODES + 255) / 256;
#pragma unroll 1
  for (int t = blockIdx.x; t < NT; t += gridDim.x) {
    const int base = t * 256 + wv * 32;

    // ---- reload z C-layout; lanes 32+ are rows 8..15 = exact zeros ----
    int4v zv = {0, 0, 0, 0};
    if (ln < 32) zv = zbuf[(size_t)(t * 8 + wv) * 32 + ln];

    // ---- L4 B-frags: direct feed, K padded to 32 (regs 2,3 zero) ----
    int4v b4g0, b4g1;
    b4g0.x = zv.x; b4g0.y = zv.y; b4g0.z = 0; b4g0.w = 0;
    b4g1.x = zv.z; b4g1.y = zv.w; b4g1.z = 0; b4g1.w = 0;

    // ---- L4: 6 -> 128 -> L5 B-frags (in-lane, permuted-k W5) ----
    int4v c5g0_0, c5g0_1, c5g0_2, c5g0_3;
    int4v c5g1_0, c5g1_1, c5g1_2, c5g1_3;
    L4_PAIR(0, c5g0_0, c5g1_0);
    L4_PAIR(1, c5g0_1, c5g1_1);
    L4_PAIR(2, c5g0_2, c5g1_2);
    L4_PAIR(3, c5g0_3, c5g1_3);

    // ---- L5: 128 -> 256 fused with L6: out = sigmoid(tanh(d).Wo + bo) ----
    float part0 = 0.0f, part1 = 0.0f;
    L5_MI(0);  L5_MI(1);  L5_MI(2);  L5_MI(3);
    L5_MI(4);  L5_MI(5);  L5_MI(6);  L5_MI(7);
    L5_MI(8);  L5_MI(9);  L5_MI(10); L5_MI(11);
    L5_MI(12); L5_MI(13); L5_MI(14); L5_MI(15);

    part0 += __shfl_xor(part0, 16, 64); part0 += __shfl_xor(part0, 32, 64);
    part1 += __shfl_xor(part1, 16, 64); part1 += __shfl_xor(part1, 32, 64);
    if (q < 2) {
      int node = base + q * 16 + c;
      if (node < N_NODES) {
        float v = ((q == 0) ? part0 : part1) + bo;
        out[node] = sigmoid_f(v);
      }
    }
  }
}

extern "C" void kernel_launch(void* const* d_in, const int* in_sizes, int n_in,
                              void* d_out, int out_size, void* d_ws, size_t ws_size,
                              hipStream_t stream) {
  (void)in_sizes; (void)n_in; (void)ws_size; (void)out_size;
  const float* ea  = (const float*)d_in[2];
  const float* W1  = (const float*)d_in[3];
  const float* b1  = (const float*)d_in[4];
  const float* We1 = (const float*)d_in[5];
  const float* be1 = (const float*)d_in[6];
  const float* We2 = (const float*)d_in[7];
  const float* be2 = (const float*)d_in[8];
  const float* Wd1 = (const float*)d_in[9];
  const float* bd1 = (const float*)d_in[10];
  const float* Wd2 = (const float*)d_in[11];
  const float* bd2 = (const float*)d_in[12];
  const float* Wo  = (const float*)d_in[13];
  const float* bo  = (const float*)d_in[14];

  gnn_prep<<<dim3((IMG_BYTES / 4 + 255) / 256), dim3(256), 0, stream>>>(
      W1, b1, We1, be1, We2, be2, Wd1, bd1, Wd2, bd2, Wo);
  gnn_k1<<<dim3(512), dim3(512), 0, stream>>>(ea, (int4v*)d_ws);
  gnn_k2<<<dim3(512), dim3(512), 0, stream>>>((const int4v*)d_ws, (float*)d_out, bo);
}

// Round 7
// 241.244 us; speedup vs baseline: 4.0845x; 1.0333x over previous
//
#include <hip/hip_runtime.h>

// Per-node MLP 16->256->128->6->128->256->1 (tanh...sigmoid) on
// edge_attr.reshape(500000,16). x / edge_index are dead inputs.
//
// R7: R6 structure kept (split kernels, in-lane C->B via permuted-k weights,
// zero bank conflicts). New: tanh(x)=2*sigma(2x)-1 folded into weights at
// prep time: producer W,b scaled by -2*log2(e) (MFMA output IS the exp2
// argument), consumer W doubled, consumer b shifted by -Sum_k W[k,:].
// Activation: s = rcp(1+exp2(y)) -- 3 ops vs 5. L1 A-zeroing via address
// select against an LDS zero block (2 cndmask/pair vs 8).

#define N_NODES 500000

// ---- weight-image layout in g_img (bytes) ----
#define OFF_W1 0        // 16 x 512B  (L1: K=16, standard k-order, x -2log2e)
#define OFF_W2 8192     // 64 x 1KB   (L2, permuted k, x -4log2e)
#define OFF_W3 73728    // 4  x 1KB   (L3, permuted k, x -4log2e)
#define OFF_W4 77824    // 8  x 1KB   (L4: z C-layout feed, x -4log2e)
#define OFF_W5 86016    // 64 x 1KB   (L5, permuted k, x -4log2e)
#define OFF_WO 151552   // 256 f32 (2*Wo)
#define OFF_B1 152576   // 256 f32 (S*b1)
#define OFF_B2 153600   // 128 f32 (S*(be1 - colsum We1))
#define OFF_B3 154112   // 16 f32  (S*(be2 - colsum We2), 6 valid)
#define OFF_B4 154176   // 128 f32 (S*(bd1 - colsum Wd1))
#define OFF_B5 154688   // 256 f32 (S*(bd2 - colsum Wd2))
#define OFF_EXTRA 155712 // 16B: [0] = bo - Sum Wo
#define OFF_ZERO  155728 // 512B zeros (L1 K-pad A rows)
#define IMG_END   156240
#define IMG_ALLOC 156672

// ---- K1 LDS: [W1 W2 W3][B1 B2 B3][Z] ----
#define K1_B1    77824
#define K1_B2    78848
#define K1_B3    79360
#define K1_Z     79872
#define K1_LDS   80384     // 5024 chunks; x2 blocks = 160768 <= 163840
// ---- K2 LDS: [W4][W5 WO][B4 B5] ----
#define K2_LDS   76800
#define K2_W4    0
#define K2_W5    8192
#define K2_WO    73728
#define K2_B4    74752
#define K2_B5    75264

#define SCONST (-2.8853900817779268f)   // -2*log2(e)

typedef _Float16 half8  __attribute__((ext_vector_type(8)));
typedef __fp16   pk16x2 __attribute__((ext_vector_type(2)));
typedef float    f32x4  __attribute__((ext_vector_type(4)));
typedef int      int4v  __attribute__((ext_vector_type(4)));

__device__ __align__(16) char g_img[IMG_ALLOC];

static __device__ __forceinline__ unsigned pack_f16_rne(float a, float b) {
  _Float16 ha = (_Float16)a, hb = (_Float16)b;
  unsigned short ua = __builtin_bit_cast(unsigned short, ha);
  unsigned short ub = __builtin_bit_cast(unsigned short, hb);
  return (unsigned)ua | ((unsigned)ub << 16);
}
static __device__ __forceinline__ int pkrtz(float a, float b) {
  pk16x2 h = __builtin_amdgcn_cvt_pkrtz(a, b);
  return __builtin_bit_cast(int, h);
}
// s = 1/(1+2^y); with y = -2*log2e*(Wx+b) this is sigma(2*(Wx+b)).
static __device__ __forceinline__ float sig2(float y) {
  float e = __builtin_amdgcn_exp2f(y);
  return __builtin_amdgcn_rcpf(1.0f + e);
}
static __device__ __forceinline__ float sigmoid_f(float x) {
  float e = __builtin_amdgcn_exp2f(x * -1.4426950408889634f);
  return __builtin_amdgcn_rcpf(1.0f + e);
}
static __device__ __forceinline__ f32x4 mfma16(half8 a, int4v b, f32x4 c) {
  return __builtin_amdgcn_mfma_f32_16x16x32_f16(a, __builtin_bit_cast(half8, b), c, 0, 0, 0);
}
static __device__ __forceinline__ half8 lda(const char* smem, int off) {
  return *(const half8*)(smem + off);
}
static __device__ __forceinline__ f32x4 ldf4(const char* smem, int off) {
  return *(const f32x4*)(smem + off);
}
#define FENCE() __builtin_amdgcn_sched_barrier(0)

struct PK2 { int lo, hi; };
static __device__ __forceinline__ PK2 tp(f32x4 a) {
  PK2 p;
  p.lo = pkrtz(sig2(a.x), sig2(a.y));
  p.hi = pkrtz(sig2(a.z), sig2(a.w));
  return p;
}

// ---------------- prep ----------------
// A-fragment layouts as in R6; all hidden producers scaled by SCONST, and
// consumers of sigma-activations get W*2 and b -= colsum(W).
__global__ void gnn_prep(const float* __restrict__ W1,  const float* __restrict__ b1,
                         const float* __restrict__ We1, const float* __restrict__ be1,
                         const float* __restrict__ We2, const float* __restrict__ be2,
                         const float* __restrict__ Wd1, const float* __restrict__ bd1,
                         const float* __restrict__ Wd2, const float* __restrict__ bd2,
                         const float* __restrict__ Wo,  const float* __restrict__ bo)
{
  int t = blockIdx.x * 256 + threadIdx.x;
  int off = t * 4;
  if (off >= IMG_END) return;
  unsigned val;
  if (off < OFF_W2) {                     // L1 (K=16): standard order, S*W1
    int rel = off;
    int mi = rel >> 9, li = (rel >> 4) & 31, j2 = (rel >> 2) & 3;
    int fout = mi * 16 + (li & 15);
    int k0 = (li >> 4) * 8 + j2 * 2;
    val = pack_f16_rne(SCONST * W1[k0 * 256 + fout], SCONST * W1[(k0 + 1) * 256 + fout]);
  } else if (off < OFF_W3) {              // L2: permuted k, 2S*We1
    int rel = off - OFF_W2;
    int blk = rel >> 10, li = (rel >> 4) & 63, j2 = (rel >> 2) & 3;
    int mi = blk >> 3, ki = blk & 7;
    int fout = mi * 16 + (li & 15);
    int k0 = ki * 32 + 4 * (li >> 4) + 16 * (j2 >> 1) + 2 * (j2 & 1);
    val = pack_f16_rne(2.0f * SCONST * We1[k0 * 128 + fout],
                       2.0f * SCONST * We1[(k0 + 1) * 128 + fout]);
  } else if (off < OFF_W4) {              // L3: permuted k, 2S*We2 (fout pad 16)
    int rel = off - OFF_W3;
    int ki = rel >> 10, li = (rel >> 4) & 63, j2 = (rel >> 2) & 3;
    int fo = li & 15;
    int k0 = ki * 32 + 4 * (li >> 4) + 16 * (j2 >> 1) + 2 * (j2 & 1);
    float a = (fo < 6) ? 2.0f * SCONST * We2[k0 * 6 + fo] : 0.0f;
    float b = (fo < 6) ? 2.0f * SCONST * We2[(k0 + 1) * 6 + fo] : 0.0f;
    val = pack_f16_rne(a, b);
  } else if (off < OFF_W5) {              // L4: z C-layout feed, 2S*Wd1
    int rel = off - OFF_W4;
    int mi = rel >> 10, li = (rel >> 4) & 63, j2 = (rel >> 2) & 3;
    int fout = mi * 16 + (li & 15);
    int qa = li >> 4;
    unsigned v = 0;
    if (j2 < 2) {
      int k0 = 4 * qa + 2 * j2;
      float a = (k0 < 6)     ? 2.0f * SCONST * Wd1[k0 * 128 + fout]       : 0.0f;
      float b = (k0 + 1 < 6) ? 2.0f * SCONST * Wd1[(k0 + 1) * 128 + fout] : 0.0f;
      v = pack_f16_rne(a, b);
    }
    val = v;
  } else if (off < OFF_WO) {              // L5: permuted k, 2S*Wd2
    int rel = off - OFF_W5;
    int blk = rel >> 10, li = (rel >> 4) & 63, j2 = (rel >> 2) & 3;
    int mi = blk >> 2, ki = blk & 3;
    int fout = mi * 16 + (li & 15);
    int k0 = ki * 32 + 4 * (li >> 4) + 16 * (j2 >> 1) + 2 * (j2 & 1);
    val = pack_f16_rne(2.0f * SCONST * Wd2[k0 * 256 + fout],
                       2.0f * SCONST * Wd2[(k0 + 1) * 256 + fout]);
  } else if (off < OFF_B1) {              // wo' = 2*Wo
    val = __builtin_bit_cast(unsigned, 2.0f * Wo[(off - OFF_WO) >> 2]);
  } else if (off < OFF_B2) {              // S*b1 (input is raw x, no shift)
    val = __builtin_bit_cast(unsigned, SCONST * b1[(off - OFF_B1) >> 2]);
  } else if (off < OFF_B3) {              // S*(be1 - colsum We1)
    int i = (off - OFF_B2) >> 2;
    float s = 0.0f;
    for (int k = 0; k < 256; ++k) s += We1[k * 128 + i];
    val = __builtin_bit_cast(unsigned, SCONST * (be1[i] - s));
  } else if (off < OFF_B4) {              // S*(be2 - colsum We2), pad 0
    int i = (off - OFF_B3) >> 2;
    float v = 0.0f;
    if (i < 6) {
      float s = 0.0f;
      for (int k = 0; k < 128; ++k) s += We2[k * 6 + i];
      v = SCONST * (be2[i] - s);
    }
    val = __builtin_bit_cast(unsigned, v);
  } else if (off < OFF_B5) {              // S*(bd1 - colsum Wd1)
    int i = (off - OFF_B4) >> 2;
    float s = 0.0f;
    for (int k = 0; k < 6; ++k) s += Wd1[k * 128 + i];
    val = __builtin_bit_cast(unsigned, SCONST * (bd1[i] - s));
  } else if (off < OFF_EXTRA) {           // S*(bd2 - colsum Wd2)
    int i = (off - OFF_B5) >> 2;
    float s = 0.0f;
    for (int k = 0; k < 128; ++k) s += Wd2[k * 256 + i];
    val = __builtin_bit_cast(unsigned, SCONST * (bd2[i] - s));
  } else if (off == OFF_EXTRA) {          // bo' = bo - Sum Wo
    float s = 0.0f;
    for (int k = 0; k < 256; ++k) s += Wo[k];
    val = __builtin_bit_cast(unsigned, bo[0] - s);
  } else {                                // rest of extra slot + zero block
    val = 0;
  }
  *(unsigned*)(g_img + off) = val;
}

static __device__ __forceinline__ void stage_chunk(const char* src, char* dst) {
  __builtin_amdgcn_global_load_lds(
      (const __attribute__((address_space(1))) void*)src,
      (__attribute__((address_space(3))) void*)dst, 16, 0, 0);
}

// ================= K1: L1 -> L2 -> L3, z (sigma form) to d_ws =================
#define L1_PAIR(KO, OUT_G0, OUT_G1) do {                                   \
    half8 Ae = lda(smem, w1b + (2*(KO))*w1s);                              \
    half8 Ao = lda(smem, w1b + (2*(KO)+1)*w1s);                            \
    f32x4 be_ = ldf4(smem, K1_B1 + (2*(KO))*64 + q*16);                    \
    f32x4 bo_ = ldf4(smem, K1_B1 + (2*(KO)+1)*64 + q*16);                  \
    f32x4 ae0 = mfma16(Ae, b1g0, be_);                                     \
    f32x4 ae1 = mfma16(Ae, b1g1, be_);                                     \
    f32x4 ao0 = mfma16(Ao, b1g0, bo_);                                     \
    f32x4 ao1 = mfma16(Ao, b1g1, bo_);                                     \
    PK2 pe0 = tp(ae0), po0 = tp(ao0), pe1 = tp(ae1), po1 = tp(ao1);        \
    OUT_G0.x = pe0.lo; OUT_G0.y = pe0.hi; OUT_G0.z = po0.lo; OUT_G0.w = po0.hi; \
    OUT_G1.x = pe1.lo; OUT_G1.y = pe1.hi; OUT_G1.z = po1.lo; OUT_G1.w = po1.hi; \
    FENCE();                                                               \
  } while (0)

#define L2_MI(MI, ACC0, ACC1) do {                                                            \
    f32x4 bb = ldf4(smem, K1_B2 + (MI)*64 + q*16);                                            \
    ACC0 = bb; ACC1 = bb;                                                                     \
    half8 A;                                                                                  \
    A = lda(smem, OFF_W2 + ((MI)*8+0)*1024 + ln*16); ACC0 = mfma16(A, c2g0_0, ACC0); ACC1 = mfma16(A, c2g1_0, ACC1); \
    A = lda(smem, OFF_W2 + ((MI)*8+1)*1024 + ln*16); ACC0 = mfma16(A, c2g0_1, ACC0); ACC1 = mfma16(A, c2g1_1, ACC1); \
    A = lda(smem, OFF_W2 + ((MI)*8+2)*1024 + ln*16); ACC0 = mfma16(A, c2g0_2, ACC0); ACC1 = mfma16(A, c2g1_2, ACC1); \
    A = lda(smem, OFF_W2 + ((MI)*8+3)*1024 + ln*16); ACC0 = mfma16(A, c2g0_3, ACC0); ACC1 = mfma16(A, c2g1_3, ACC1); \
    A = lda(smem, OFF_W2 + ((MI)*8+4)*1024 + ln*16); ACC0 = mfma16(A, c2g0_4, ACC0); ACC1 = mfma16(A, c2g1_4, ACC1); \
    A = lda(smem, OFF_W2 + ((MI)*8+5)*1024 + ln*16); ACC0 = mfma16(A, c2g0_5, ACC0); ACC1 = mfma16(A, c2g1_5, ACC1); \
    A = lda(smem, OFF_W2 + ((MI)*8+6)*1024 + ln*16); ACC0 = mfma16(A, c2g0_6, ACC0); ACC1 = mfma16(A, c2g1_6, ACC1); \
    A = lda(smem, OFF_W2 + ((MI)*8+7)*1024 + ln*16); ACC0 = mfma16(A, c2g0_7, ACC0); ACC1 = mfma16(A, c2g1_7, ACC1); \
  } while (0)

#define L2_PAIR(KO, OUT_G0, OUT_G1) do {                                   \
    f32x4 ve0, ve1, vo0, vo1;                                              \
    L2_MI(2*(KO),   ve0, ve1);                                             \
    FENCE();                                                               \
    L2_MI(2*(KO)+1, vo0, vo1);                                             \
    PK2 pe0 = tp(ve0), po0 = tp(vo0), pe1 = tp(ve1), po1 = tp(vo1);        \
    OUT_G0.x = pe0.lo; OUT_G0.y = pe0.hi; OUT_G0.z = po0.lo; OUT_G0.w = po0.hi; \
    OUT_G1.x = pe1.lo; OUT_G1.y = pe1.hi; OUT_G1.z = po1.lo; OUT_G1.w = po1.hi; \
    FENCE();                                                               \
  } while (0)

__global__ __launch_bounds__(512)
void gnn_k1(const float* __restrict__ ea, int4v* __restrict__ zbuf)
{
  __shared__ __align__(16) char smem[K1_LDS];
  const int tid = threadIdx.x;
  const int wv = tid >> 6, ln = tid & 63;

#pragma unroll 1
  for (int r = 0; r < 10; ++r) {
    int cb = (r * 8 + wv) << 6;
    if (cb < 5024) {
      int src;
      if (cb < 4864)      src = cb * 16;
      else if (cb < 4992) src = OFF_B1 + (cb - 4864) * 16;
      else                src = OFF_ZERO + (cb - 4992) * 16;
      stage_chunk(g_img + src + ln * 16, smem + (size_t)cb * 16 + ln * 16);
    }
  }
  __syncthreads();

  const int q = ln >> 4, c = ln & 15;
  const bool qlo = (q < 2);
  // L1 A: lanes with k>=16 (q>=2) read the zero block instead of cndmask'ing.
  const int lnl16 = (ln & 31) * 16;
  const int w1b = qlo ? (OFF_W1 + lnl16) : (K1_Z + lnl16);
  const int w1s = qlo ? 512 : 0;

  const int NT = (N_NODES + 255) / 256;
#pragma unroll 1
  for (int t = blockIdx.x; t < NT; t += gridDim.x) {
    const int base = t * 256 + wv * 32;

    // ---- L1 input: edge_attr as X^T (garbage in k>=16 lanes is fine: A=0) ----
    int nl = base + (q >> 1) * 16 + c;
    if (nl > N_NODES - 1) nl = N_NODES - 1;
    const f32x4* ea4 = (const f32x4*)ea;
    size_t eb = (size_t)nl * 4 + (size_t)((q & 1) * 2);
    f32x4 vlo = ea4[eb];
    f32x4 vhi = ea4[eb + 1];
    int4v b1g0;
    b1g0.x = pkrtz(vlo.x, vlo.y); b1g0.y = pkrtz(vlo.z, vlo.w);
    b1g0.z = pkrtz(vhi.x, vhi.y); b1g0.w = pkrtz(vhi.z, vhi.w);
    int sh = (ln + 32) & 63;
    int4v b1g1;
    b1g1.x = __shfl(b1g0.x, sh, 64); b1g1.y = __shfl(b1g0.y, sh, 64);
    b1g1.z = __shfl(b1g0.z, sh, 64); b1g1.w = __shfl(b1g0.w, sh, 64);

    // ---- L1: 16 -> 256 -> L2 B-frags (in-lane) ----
    int4v c2g0_0, c2g0_1, c2g0_2, c2g0_3, c2g0_4, c2g0_5, c2g0_6, c2g0_7;
    int4v c2g1_0, c2g1_1, c2g1_2, c2g1_3, c2g1_4, c2g1_5, c2g1_6, c2g1_7;
    L1_PAIR(0, c2g0_0, c2g1_0);
    L1_PAIR(1, c2g0_1, c2g1_1);
    L1_PAIR(2, c2g0_2, c2g1_2);
    L1_PAIR(3, c2g0_3, c2g1_3);
    L1_PAIR(4, c2g0_4, c2g1_4);
    L1_PAIR(5, c2g0_5, c2g1_5);
    L1_PAIR(6, c2g0_6, c2g1_6);
    L1_PAIR(7, c2g0_7, c2g1_7);

    // ---- L2: 256 -> 128 -> L3 B-frags ----
    int4v c3g0_0, c3g0_1, c3g0_2, c3g0_3;
    int4v c3g1_0, c3g1_1, c3g1_2, c3g1_3;
    L2_PAIR(0, c3g0_0, c3g1_0);
    L2_PAIR(1, c3g0_1, c3g1_1);
    L2_PAIR(2, c3g0_2, c3g1_2);
    L2_PAIR(3, c3g0_3, c3g1_3);

    // ---- L3: 128 -> 6 ----
    f32x4 bb3 = ldf4(smem, K1_B3 + q * 16);
    f32x4 z0 = bb3, z1 = bb3;
    half8 A;
    A = lda(smem, OFF_W3 + 0 * 1024 + ln * 16); z0 = mfma16(A, c3g0_0, z0); z1 = mfma16(A, c3g1_0, z1);
    A = lda(smem, OFF_W3 + 1 * 1024 + ln * 16); z0 = mfma16(A, c3g0_1, z0); z1 = mfma16(A, c3g1_1, z1);
    A = lda(smem, OFF_W3 + 2 * 1024 + ln * 16); z0 = mfma16(A, c3g0_2, z0); z1 = mfma16(A, c3g1_2, z1);
    A = lda(smem, OFF_W3 + 3 * 1024 + ln * 16); z0 = mfma16(A, c3g0_3, z0); z1 = mfma16(A, c3g1_3, z1);
    PK2 p3g0 = tp(z0);
    PK2 p3g1 = tp(z1);

    // ---- store z (sigma) C-layout; rows 0..7 on lanes 0..31 ----
    if (ln < 32) {
      int4v zv;
      zv.x = p3g0.lo; zv.y = p3g0.hi; zv.z = p3g1.lo; zv.w = p3g1.hi;
      zbuf[(size_t)(t * 8 + wv) * 32 + ln] = zv;
    }
  }
}

// ================= K2: L4 -> L5 -> out =================
#define L4_MI(MI, ACC0, ACC1) do {                                         \
    f32x4 bb = ldf4(smem, K2_B4 + (MI)*64 + q*16);                         \
    half8 A = lda(smem, K2_W4 + (MI)*1024 + ln*16);                        \
    ACC0 = mfma16(A, b4g0, bb);                                            \
    ACC1 = mfma16(A, b4g1, bb);                                            \
  } while (0)

#define L4_PAIR(KO, OUT_G0, OUT_G1) do {                                   \
    f32x4 ve0, ve1, vo0, vo1;                                              \
    L4_MI(2*(KO),   ve0, ve1);                                             \
    L4_MI(2*(KO)+1, vo0, vo1);                                             \
    PK2 pe0 = tp(ve0), po0 = tp(vo0), pe1 = tp(ve1), po1 = tp(vo1);        \
    OUT_G0.x = pe0.lo; OUT_G0.y = pe0.hi; OUT_G0.z = po0.lo; OUT_G0.w = po0.hi; \
    OUT_G1.x = pe1.lo; OUT_G1.y = pe1.hi; OUT_G1.z = po1.lo; OUT_G1.w = po1.hi; \
    FENCE();                                                               \
  } while (0)

#define L5_MI(MI) do {                                                                        \
    f32x4 bb = ldf4(smem, K2_B5 + (MI)*64 + q*16);                                            \
    f32x4 a0 = bb, a1 = bb;                                                                   \
    half8 A;                                                                                  \
    A = lda(smem, K2_W5 + ((MI)*4+0)*1024 + ln*16); a0 = mfma16(A, c5g0_0, a0); a1 = mfma16(A, c5g1_0, a1); \
    A = lda(smem, K2_W5 + ((MI)*4+1)*1024 + ln*16); a0 = mfma16(A, c5g0_1, a0); a1 = mfma16(A, c5g1_1, a1); \
    A = lda(smem, K2_W5 + ((MI)*4+2)*1024 + ln*16); a0 = mfma16(A, c5g0_2, a0); a1 = mfma16(A, c5g1_2, a1); \
    A = lda(smem, K2_W5 + ((MI)*4+3)*1024 + ln*16); a0 = mfma16(A, c5g0_3, a0); a1 = mfma16(A, c5g1_3, a1); \
    f32x4 wo = ldf4(smem, K2_WO + (MI)*64 + q*16);                                            \
    part0 += sig2(a0.x)*wo.x + sig2(a0.y)*wo.y + sig2(a0.z)*wo.z + sig2(a0.w)*wo.w;           \
    part1 += sig2(a1.x)*wo.x + sig2(a1.y)*wo.y + sig2(a1.z)*wo.z + sig2(a1.w)*wo.w;           \
    FENCE();                                                                                  \
  } while (0)

__global__ __launch_bounds__(512)
void gnn_k2(const int4v* __restrict__ zbuf, float* __restrict__ out)
{
  __shared__ __align__(16) char smem[K2_LDS];
  const int tid = threadIdx.x;
  const int wv = tid >> 6, ln = tid & 63;

#pragma unroll 1
  for (int r = 0; r < 10; ++r) {
    int cb = (r * 8 + wv) << 6;
    if (cb < 4800) {
      int src;
      if (cb < 512)       src = OFF_W4 + cb * 16;
      else if (cb < 4672) src = OFF_W5 + (cb - 512) * 16;   // W5+WO contiguous
      else                src = OFF_B4 + (cb - 4672) * 16;
      stage_chunk(g_img + src + ln * 16, smem + (size_t)cb * 16 + ln * 16);
    }
  }
  __syncthreads();

  const int q = ln >> 4, c = ln & 15;
  const float bo2 = *(const float*)(g_img + OFF_EXTRA);   // bo - Sum Wo

  const int NT = (N_NODES + 255) / 256;
#pragma unroll 1
  for (int t = blockIdx.x; t < NT; t += gridDim.x) {
    const int base = t * 256 + wv * 32;

    // ---- reload z (sigma); lanes 32+ rows have zero W4 rows anyway ----
    int4v zv = {0, 0, 0, 0};
    if (ln < 32) zv = zbuf[(size_t)(t * 8 + wv) * 32 + ln];

    int4v b4g0, b4g1;
    b4g0.x = zv.x; b4g0.y = zv.y; b4g0.z = 0; b4g0.w = 0;
    b4g1.x = zv.z; b4g1.y = zv.w; b4g1.z = 0; b4g1.w = 0;

    // ---- L4: 6 -> 128 -> L5 B-frags ----
    int4v c5g0_0, c5g0_1, c5g0_2, c5g0_3;
    int4v c5g1_0, c5g1_1, c5g1_2, c5g1_3;
    L4_PAIR(0, c5g0_0, c5g1_0);
    L4_PAIR(1, c5g0_1, c5g1_1);
    L4_PAIR(2, c5g0_2, c5g1_2);
    L4_PAIR(3, c5g0_3, c5g1_3);

    // ---- L5 + output: out = sigma(Sum wo'*s5 + bo') ----
    float part0 = 0.0f, part1 = 0.0f;
    L5_MI(0);  L5_MI(1);  L5_MI(2);  L5_MI(3);
    L5_MI(4);  L5_MI(5);  L5_MI(6);  L5_MI(7);
    L5_MI(8);  L5_MI(9);  L5_MI(10); L5_MI(11);
    L5_MI(12); L5_MI(13); L5_MI(14); L5_MI(15);

    part0 += __shfl_xor(part0, 16, 64); part0 += __shfl_xor(part0, 32, 64);
    part1 += __shfl_xor(part1, 16, 64); part1 += __shfl_xor(part1, 32, 64);
    if (q < 2) {
      int node = base + q * 16 + c;
      if (node < N_NODES) {
        float v = ((q == 0) ? part0 : part1) + bo2;
        out[node] = sigmoid_f(v);
      }
    }
  }
}

extern "C" void kernel_launch(void* const* d_in, const int* in_sizes, int n_in,
                              void* d_out, int out_size, void* d_ws, size_t ws_size,
                              hipStream_t stream) {
  (void)in_sizes; (void)n_in; (void)ws_size; (void)out_size;
  const float* ea  = (const float*)d_in[2];
  const float* W1  = (const float*)d_in[3];
  const float* b1  = (const float*)d_in[4];
  const float* We1 = (const float*)d_in[5];
  const float* be1 = (const float*)d_in[6];
  const float* We2 = (const float*)d_in[7];
  const float* be2 = (const float*)d_in[8];
  const float* Wd1 = (const float*)d_in[9];
  const float* bd1 = (const float*)d_in[10];
  const float* Wd2 = (const float*)d_in[11];
  const float* bd2 = (const float*)d_in[12];
  const float* Wo  = (const float*)d_in[13];
  const float* bo  = (const float*)d_in[14];

  gnn_prep<<<dim3((IMG_END / 4 + 255) / 256), dim3(256), 0, stream>>>(
      W1, b1, We1, be1, We2, be2, Wd1, bd1, Wd2, bd2, Wo, bo);
  gnn_k1<<<dim3(512), dim3(512), 0, stream>>>(ea, (int4v*)d_ws);
  gnn_k2<<<dim3(512), dim3(512), 0, stream>>>((const int4v*)d_ws, (float*)d_out);
}